// Round 4
// baseline (1103.315 us; speedup 1.0000x reference)
//
#include <hip/hip_runtime.h>
#include <float.h>
#include <math.h>

#define TOKENS 16384
#define DIM    7168
#define NEXP   256
#define BM     64           // tokens per block
#define BK     32
#define NCHUNK (DIM / BK)   // 224
#define ROUTE_SCALE 2.5
#define TAU      6e-6f      // ~50x rms score error of the fp16-split path
#define WSCALE   1024.0f    // lifts W_lo out of fp16 denormal range (exact pow2)
#define WUNSCALE 0.0009765625f

typedef _Float16 half8  __attribute__((ext_vector_type(8)));
typedef _Float16 half4v __attribute__((ext_vector_type(4)));
typedef float    f32x4  __attribute__((ext_vector_type(4)));

#define WPLANE 1835008      // 256*7168 halves per plane

__device__ __forceinline__ _Float16 hi16(float f) { return (_Float16)f; }
__device__ __forceinline__ _Float16 lo16(float f) {
    _Float16 h = (_Float16)f;
    return (_Float16)(f - (float)h);
}

// ---------------- Kernel 0: split (W*1024) into fp16 hi/lo planes, CHUNK-MAJOR ----------------
__global__ __launch_bounds__(256)
void conv_w(const float* __restrict__ W, _Float16* __restrict__ Wh, _Float16* __restrict__ Wl,
            int* __restrict__ cnt) {
    if (blockIdx.x == 0 && threadIdx.x == 0) *cnt = 0;
    int i = blockIdx.x * 256 + threadIdx.x;       // over 458752 float4s (exact)
    int f = i * 4;
    int e = f / DIM;
    int k = f - e * DIM;
    float4 v = ((const float4*)W)[i];
    v.x *= WSCALE; v.y *= WSCALE; v.z *= WSCALE; v.w *= WSCALE;
    half4v h, l;
    h[0] = hi16(v.x); l[0] = lo16(v.x);
    h[1] = hi16(v.y); l[1] = lo16(v.y);
    h[2] = hi16(v.z); l[2] = lo16(v.z);
    h[3] = hi16(v.w); l[3] = lo16(v.w);
    int o = ((k >> 5) << 13) + (e << 5) + (k & 31);   // chunk-major offset
    *(half4v*)(Wh + o) = h;
    *(half4v*)(Wl + o) = l;
}

// ---------------- asm pipeline primitives ----------------
#define MFMA16(a, b, c) __builtin_amdgcn_mfma_f32_16x16x32_f16(a, b, c, 0, 0, 0)

#define VWAIT(n) do { \
    asm volatile("s_waitcnt vmcnt(" #n ")" ::: "memory"); \
    __builtin_amdgcn_sched_barrier(0); \
} while (0)

// one W chunk (4 x dwordx4) into named set S; n=1 tile at +512 halves = +1024 B imm
#define ISSUE_WS(c, S) do { \
    const _Float16* _p = wph0 + (size_t)(c) * 8192; \
    const _Float16* _q = wpl0 + (size_t)(c) * 8192; \
    asm volatile("global_load_dwordx4 %0, %1, off"             : "=&v"(S##h0) : "v"(_p)); \
    asm volatile("global_load_dwordx4 %0, %1, off offset:1024" : "=&v"(S##h1) : "v"(_p)); \
    asm volatile("global_load_dwordx4 %0, %1, off"             : "=&v"(S##l0) : "v"(_q)); \
    asm volatile("global_load_dwordx4 %0, %1, off offset:1024" : "=&v"(S##l1) : "v"(_q)); \
} while (0)

// X for 2-chunk group gg: 8 floats per thread
#define ISSUE_X(gg) do { \
    const float* _px = xsrc + (size_t)(gg) * 64; \
    asm volatile("global_load_dwordx4 %0, %1, off"           : "=&v"(xa) : "v"(_px)); \
    asm volatile("global_load_dwordx4 %0, %1, off offset:16" : "=&v"(xb) : "v"(_px)); \
} while (0)

// A-frags from LDS + 12 MFMA (order identical to verified kernel)
#define COMPUTE(ABP, BH0, BH1, BL0, BL1) do { \
    const _Float16* _ab = (ABP); \
    half8 ah0 = *(const half8*)(_ab + abase0); \
    half8 ah1 = *(const half8*)(_ab + abase1); \
    half8 al0 = *(const half8*)(_ab + 2048 + abase0); \
    half8 al1 = *(const half8*)(_ab + 2048 + abase1); \
    __builtin_amdgcn_s_setprio(1); \
    acc00 = MFMA16(ah0, BH0, acc00); acc00 = MFMA16(ah0, BL0, acc00); acc00 = MFMA16(al0, BH0, acc00); \
    acc01 = MFMA16(ah0, BH1, acc01); acc01 = MFMA16(ah0, BL1, acc01); acc01 = MFMA16(al0, BH1, acc01); \
    acc10 = MFMA16(ah1, BH0, acc10); acc10 = MFMA16(ah1, BL0, acc10); acc10 = MFMA16(al1, BH0, acc10); \
    acc11 = MFMA16(ah1, BH1, acc11); acc11 = MFMA16(ah1, BL1, acc11); acc11 = MFMA16(al1, BH1, acc11); \
    __builtin_amdgcn_s_setprio(0); \
} while (0)

#define COMPUTE_S(ABP, S) COMPUTE(ABP, S##h0, S##h1, S##l0, S##l1)

#define DUMPF() do { \
    accf00 += acc00; acc00 = (f32x4)(0.0f); \
    accf01 += acc01; acc01 = (f32x4)(0.0f); \
    accf10 += acc10; acc10 = (f32x4)(0.0f); \
    accf11 += acc11; acc11 = (f32x4)(0.0f); \
} while (0)

#define CONVERT_WRITE_X(dstbuf) do { \
    half8 h8, l8; \
    const float v[8] = {xa.x, xa.y, xa.z, xa.w, xb.x, xb.y, xb.z, xb.w}; \
    _Pragma("unroll") \
    for (int e = 0; e < 8; ++e) { h8[e] = hi16(v[e]); l8[e] = lo16(v[e]); } \
    _Float16* d = hb + (dstbuf) * 8192 + xdst; \
    *(half8*)(d)        = h8; \
    *(half8*)(d + 2048) = l8; \
} while (0)

// ---------------- Kernel 1: fp16-split MFMA GEMM -> logits to global ----------------
// 512 threads (8 waves), tile [64 tokens] x [128 experts], grid 512 = 2 independent
// barrier domains per CU (the R0-R3 invariant was ONE 1024-thread domain; when it drained
// at a barrier/vmcnt, the CU went idle -- now the sibling block's waves fill the bubble).
// E-split with XCD mapping: eh=(bid&7)>>2 -> all 32 blocks of an XCD share one 3.67 MB
// W-half (L2-resident); both blocks of a CU share the same W slice (L1 dedup).
// X staged in LDS (fp16 hi/lo) in 2-chunk groups, double-buffered (32 KB static LDS).
// W streams global->reg, depth-2 pinned schedule. Per-(t,e) MFMA product order and the
// every-16-chunks accf dump cadence are identical to the verified kernel -> logits
// bit-identical; routing moved to gate_route (reads logits from global).
__global__ __launch_bounds__(512, 4)
void gate_main(const float* __restrict__ X, const _Float16* __restrict__ Wh,
               const _Float16* __restrict__ Wl, float* __restrict__ LG) {
    __shared__ _Float16 hb[16384];                // 32 KB: X dbuf [2 buf][2 chunks][2 planes][64][32]

    const int tid  = threadIdx.x;
    const int lane = tid & 63;
    const int wid  = tid >> 6;                    // 0..7
    const int mq   = wid >> 2;                    // 0..1  (token half: 32 rows)
    const int ns   = wid & 3;                     // 0..3  (expert slice: 32 of 128)
    const int bid  = blockIdx.x;
    const int eh   = (bid >> 2) & 1;              // E-half from (bid&7)>>2: XCD 0-3 -> 0, 4-7 -> 1
    const int mt   = (bid >> 3) * 4 + (bid & 3);  // 0..255, each (mt,eh) exactly once
    const int m0   = mt * BM;
    const int fr   = lane & 15;
    const int fk   = lane >> 4;                   // 0..3

    // X staging map: 512 units = 2 chunks x 64 rows x 4 slots
    const int xcc = tid >> 8;                     // 0..1
    const int xr  = (tid >> 2) & 63;              // 0..63
    const int xs  = tid & 3;                      // 0..3
    const float* xsrc = X + (size_t)(m0 + xr) * DIM + xcc * 32 + xs * 8;
    const int xdst = xcc * 4096 + xr * 32 + ((xs ^ ((xr >> 1) & 3)) << 3);

    // A-fragment LDS bases (halves), swizzled; per-chunk block = [hi 64x32][lo 64x32]
    const int row0 = mq * 32 + fr;
    const int row1 = row0 + 16;
    const int abase0 = row0 * 32 + ((fk ^ ((row0 >> 1) & 3)) << 3);
    const int abase1 = row1 * 32 + ((fk ^ ((row1 >> 1) & 3)) << 3);

    // W chunk-major per-lane base; expert range [eh*128, eh*128+128)
    const int wro = ((eh * 128 + ns * 32 + fr) << 5) + fk * 8;
    const _Float16* wph0 = Wh + wro;
    const _Float16* wpl0 = Wl + wro;

    f32x4 acc00 = {}, acc01 = {}, acc10 = {}, acc11 = {};
    f32x4 accf00 = {}, accf01 = {}, accf10 = {}, accf11 = {};
    half8 S0h0, S0h1, S0l0, S0l1;
    half8 S1h0, S1h1, S1l0, S1l1;
    half8 S2h0, S2h1, S2l0, S2l1;
    half8 S3h0, S3h1, S3l0, S3l1;
    float4 xa, xb;

    // ---- prologue: stage X group 0 (plain), drain, pin W(0),W(1) in flight ----
    {
        float4 pa = *(const float4*)(xsrc);
        float4 pb = *(const float4*)(xsrc + 4);
        half8 h8, l8;
        const float v[8] = {pa.x, pa.y, pa.z, pa.w, pb.x, pb.y, pb.z, pb.w};
        #pragma unroll
        for (int e = 0; e < 8; ++e) { h8[e] = hi16(v[e]); l8[e] = lo16(v[e]); }
        *(half8*)(hb + xdst)        = h8;
        *(half8*)(hb + xdst + 2048) = l8;
    }
    asm volatile("s_waitcnt vmcnt(0) lgkmcnt(0)" ::: "memory");
    __builtin_amdgcn_sched_barrier(0);
    ISSUE_WS(0, S0);
    ISSUE_WS(1, S1);
    __builtin_amdgcn_s_barrier();                 // buf0 visible; 8 W-loads in flight

    // ---- main: 55 pairs of 2-chunk groups (groups 0..109, chunks 0..219) ----
    // invariant entering pair k: S0=W(4k), S1=W(4k+1) in flight (queue 8)
    for (int k = 0; k < 55; ++k) {
        const int c4 = k * 4;
        // even group 2k (buf0, chunks 4k,4k+1)
        VWAIT(4); ISSUE_WS(c4 + 2, S2); ISSUE_X(2 * k + 1); COMPUTE_S(hb,        S0);
        VWAIT(6); ISSUE_WS(c4 + 3, S3);                     COMPUTE_S(hb + 4096, S1);
        VWAIT(4); CONVERT_WRITE_X(1);
        asm volatile("s_waitcnt lgkmcnt(0)" ::: "memory");
        __builtin_amdgcn_s_barrier();
        // odd group 2k+1 (buf1, chunks 4k+2,4k+3)
        VWAIT(4); ISSUE_WS(c4 + 4, S0); ISSUE_X(2 * k + 2); COMPUTE_S(hb + 8192,  S2);
        VWAIT(6); ISSUE_WS(c4 + 5, S1);                     COMPUTE_S(hb + 12288, S3);
        if ((k & 3) == 3) DUMPF();                // after chunk 16j+15: same cadence as verified
        VWAIT(4); CONVERT_WRITE_X(0);
        asm volatile("s_waitcnt lgkmcnt(0)" ::: "memory");
        __builtin_amdgcn_s_barrier();
    }
    // group 110 (buf0, chunks 220,221): S0=W(220), S1=W(221) in flight
    VWAIT(4); ISSUE_WS(222, S2); ISSUE_X(111); COMPUTE_S(hb,        S0);
    VWAIT(6); ISSUE_WS(223, S3);               COMPUTE_S(hb + 4096, S1);
    VWAIT(4); CONVERT_WRITE_X(1);
    asm volatile("s_waitcnt lgkmcnt(0)" ::: "memory");
    __builtin_amdgcn_s_barrier();
    // group 111 (buf1, chunks 222,223): epilogue
    VWAIT(4); COMPUTE_S(hb + 8192,  S2);
    VWAIT(0); COMPUTE_S(hb + 12288, S3);
    DUMPF();                                      // chunk 223 -> final dump, same cadence

    // ---- logits (unscaled) straight to global ----
    {
        f32x4 af[2][2] = {{accf00, accf01}, {accf10, accf11}};
        #pragma unroll
        for (int m = 0; m < 2; ++m)
            #pragma unroll
            for (int n = 0; n < 2; ++n)
                #pragma unroll
                for (int r = 0; r < 4; ++r) {
                    int t = m0 + mq * 32 + m * 16 + fk * 4 + r;   // D row = (lane>>4)*4 + reg
                    int e = eh * 128 + ns * 32 + n * 16 + fr;     // D col = lane&15
                    LG[(size_t)t * 256 + e] = af[m][n][r] * WUNSCALE;
                }
    }
}

// ---------------- Kernel 1b: routing + margin flags (verbatim serial code, 1 thread/token) ----------------
// 256 blocks x 64 threads; stages 64 rotated logit rows in LDS (rotation kills the
// 64-way same-bank serial-scan conflict), then runs the R4/R7-verified routing verbatim.
__global__ __launch_bounds__(64)
void gate_route(const float* __restrict__ LG, const float* __restrict__ Bp,
                float* __restrict__ outw, float* __restrict__ outi,
                int* __restrict__ cnt, int* __restrict__ list) {
    __shared__ float lrow[64 * 256];              // 64 KB
    const int t   = threadIdx.x;                  // 0..63
    const int gt0 = blockIdx.x * 64;

    for (int r = 0; r < 64; ++r) {                // coalesced 1 KB/row, rotated scatter
        float4 v = ((const float4*)LG)[(size_t)(gt0 + r) * 64 + t];
        int e = t * 4;
        lrow[r * 256 + ((e + 0 + r) & 255)] = v.x;
        lrow[r * 256 + ((e + 1 + r) & 255)] = v.y;
        lrow[r * 256 + ((e + 2 + r) & 255)] = v.z;
        lrow[r * 256 + ((e + 3 + r) & 255)] = v.w;
    }
    __syncthreads();

    const int gtok = gt0 + t;
    float* row = lrow + t * 256;

    for (int e = 0; e < 256; ++e) {
        int a = (e + t) & 255;
        row[a] = 1.0f / (1.0f + expf(-row[a]));
    }
    float gs[8];
    #pragma unroll
    for (int g = 0; g < 8; ++g) {
        float m1 = -FLT_MAX, m2 = -FLT_MAX;
        for (int e = g * 32; e < g * 32 + 32; ++e) {
            float v = row[(e + t) & 255] + Bp[e];
            if (v > m1) { m2 = m1; m1 = v; }
            else if (v > m2) { m2 = v; }
        }
        gs[g] = m1 + m2;
    }
    unsigned sel = 0;
    #pragma unroll
    for (int r = 0; r < 4; ++r) {
        float best = -FLT_MAX; int bg = 0;
        #pragma unroll
        for (int g = 0; g < 8; ++g)
            if (!((sel >> g) & 1) && gs[g] > best) { best = gs[g]; bg = g; }
        sel |= 1u << bg;
    }
    float selmin = FLT_MAX, unselmax = -FLT_MAX;
    #pragma unroll
    for (int g = 0; g < 8; ++g) {
        if ((sel >> g) & 1) selmin = fminf(selmin, gs[g]);
        else                unselmax = fmaxf(unselmax, gs[g]);
    }
    bool flag = (selmin - unselmax) < (2.0f * TAU);

    float pv = FLT_MAX; int pe = -1;
    float wv8[8]; int ie8[8]; float wsum = 0.f;
    for (int j = 0; j < 9; ++j) {
        float best = -FLT_MAX; int be = 0;
        for (int e = 0; e < 256; ++e) {
            float v = ((sel >> (e >> 5)) & 1) ? (row[(e + t) & 255] + Bp[e]) : 0.0f;
            bool after = (v < pv) || (v == pv && e > pe);
            if (after && v > best) { best = v; be = e; }
        }
        if (j > 0) flag = flag || ((pv - best) < TAU);
        if (j < 8) {
            float ow = row[(be + t) & 255];
            wv8[j] = ow; ie8[j] = be; wsum += ow;
        }
        pv = best; pe = be;
    }
    if (flag) {
        int slot = atomicAdd(cnt, 1);
        list[slot] = gtok;
    }
    float scale = (float)ROUTE_SCALE / wsum;
    #pragma unroll
    for (int j = 0; j < 8; ++j) {
        outw[(size_t)gtok * 8 + j] = wv8[j] * scale;
        outi[(size_t)gtok * 8 + j] = (float)ie8[j];
    }
}

// ---------------- Kernel 2: fp64 recheck of flagged tokens (compacted list, grid-stride) ----------------
__global__ __launch_bounds__(256)
void gate_fix(const float* __restrict__ X, const float* __restrict__ W,
              const float* __restrict__ Bp, float* __restrict__ outw,
              float* __restrict__ outi, const int* __restrict__ cnt,
              const int* __restrict__ list) {
    __shared__ float  xrow[DIM];
    __shared__ double sig[NEXP];
    const int tid = threadIdx.x;
    const int s   = tid >> 5;
    const int kt  = tid & 31;
    const int n   = *cnt;

    for (int li = blockIdx.x; li < n; li += 256) {
        const int t = list[li];
        __syncthreads();                          // previous iteration's readers done

        for (int i = tid * 4; i < DIM; i += 1024)
            *(float4*)(xrow + i) = *(const float4*)(X + (size_t)t * DIM + i);
        __syncthreads();

        for (int i = 0; i < 32; ++i) {
            const int e = i * 8 + s;
            const float* wrow = W + (size_t)e * DIM;
            double s0 = 0, s1 = 0, s2 = 0, s3 = 0;
            for (int c = 0; c < DIM / 128; ++c) {
                int k = c * 128 + kt * 4;
                float4 w4 = *(const float4*)(wrow + k);
                float4 x4 = *(const float4*)(xrow + k);
                s0 = fma((double)x4.x, (double)w4.x, s0);
                s1 = fma((double)x4.y, (double)w4.y, s1);
                s2 = fma((double)x4.z, (double)w4.z, s2);
                s3 = fma((double)x4.w, (double)w4.w, s3);
            }
            double d = (s0 + s1) + (s2 + s3);
            #pragma unroll
            for (int m = 16; m >= 1; m >>= 1)
                d += __shfl_xor(d, m, 32);
            if (kt == 0) sig[e] = 1.0 / (1.0 + exp(-d));
        }
        __syncthreads();

        if (tid == 0) {
            const double* row = sig;
            double gs[8];
            #pragma unroll
            for (int g = 0; g < 8; ++g) {
                double m1 = -DBL_MAX, m2 = -DBL_MAX;
                for (int e = g * 32; e < g * 32 + 32; ++e) {
                    double v = row[e] + (double)Bp[e];
                    if (v > m1) { m2 = m1; m1 = v; }
                    else if (v > m2) { m2 = v; }
                }
                gs[g] = m1 + m2;
            }
            unsigned sel = 0;
            #pragma unroll
            for (int r = 0; r < 4; ++r) {
                double best = -DBL_MAX; int bg = 0;
                #pragma unroll
                for (int g = 0; g < 8; ++g)
                    if (!((sel >> g) & 1) && gs[g] > best) { best = gs[g]; bg = g; }
                sel |= 1u << bg;
            }
            double pv = DBL_MAX; int pe = -1;
            double wv8[8]; int ie8[8]; double wsum = 0.0;
            #pragma unroll
            for (int j = 0; j < 8; ++j) {
                double best = -DBL_MAX; int be = 0;
                for (int e = 0; e < 256; ++e) {
                    double v = ((sel >> (e >> 5)) & 1) ? (row[e] + (double)Bp[e]) : 0.0;
                    bool after = (v < pv) || (v == pv && e > pe);
                    if (after && v > best) { best = v; be = e; }
                }
                double ow = row[be];
                wv8[j] = ow; ie8[j] = be; wsum += ow;
                pv = best; pe = be;
            }
            #pragma unroll
            for (int j = 0; j < 8; ++j) {
                outw[(size_t)t * 8 + j] = (float)((wv8[j] / wsum) * ROUTE_SCALE);
                outi[(size_t)t * 8 + j] = (float)ie8[j];
            }
        }
    }
}

extern "C" void kernel_launch(void* const* d_in, const int* in_sizes, int n_in,
                              void* d_out, int out_size, void* d_ws, size_t ws_size,
                              hipStream_t stream) {
    const float* X  = (const float*)d_in[0];
    const float* W  = (const float*)d_in[1];
    const float* Bp = (const float*)d_in[2];
    float* outw = (float*)d_out;
    float* outi = (float*)d_out + (size_t)TOKENS * 8;

    _Float16* Wh = (_Float16*)d_ws;                          // 3.67 MB (chunk-major)
    _Float16* Wl = Wh + WPLANE;                              // 3.67 MB (chunk-major)
    int* cnt  = (int*)(Wl + WPLANE);                         // 16 B slot
    int* list = (int*)((char*)cnt + 16);                     // 64 KB
    float* LG = (float*)(list + TOKENS);                     // 16.8 MB logits (16B-aligned)

    conv_w    <<<dim3(WPLANE / 1024), dim3(256), 0, stream>>>(W, Wh, Wl, cnt);
    gate_main <<<dim3(512),           dim3(512), 0, stream>>>(X, Wh, Wl, LG);
    gate_route<<<dim3(TOKENS / 64),   dim3(64),  0, stream>>>(LG, Bp, outw, outi, cnt, list);
    gate_fix  <<<dim3(256),           dim3(256), 0, stream>>>(X, W, Bp, outw, outi, cnt, list);
}

// Round 5
// 946.691 us; speedup vs baseline: 1.1654x; 1.1654x over previous
//
#include <hip/hip_runtime.h>
#include <float.h>
#include <math.h>

#define TOKENS 16384
#define DIM    7168
#define NEXP   256
#define BM     64           // tokens per block
#define BK     32
#define NCHUNK (DIM / BK)   // 224
#define ROUTE_SCALE 2.5
#define TAU      6e-6f      // ~50x rms score error of the fp16-split path
#define WSCALE   1024.0f    // lifts W_lo out of fp16 denormal range (exact pow2)
#define WUNSCALE 0.0009765625f

typedef _Float16 half8  __attribute__((ext_vector_type(8)));
typedef _Float16 half4v __attribute__((ext_vector_type(4)));
typedef float    f32x4  __attribute__((ext_vector_type(4)));

#define WPLANE 1835008      // 256*7168 halves per plane

__device__ __forceinline__ _Float16 hi16(float f) { return (_Float16)f; }
__device__ __forceinline__ _Float16 lo16(float f) {
    _Float16 h = (_Float16)f;
    return (_Float16)(f - (float)h);
}

// ---------------- Kernel 0: split (W*1024) into fp16 hi/lo planes, CHUNK-MAJOR ----------------
__global__ __launch_bounds__(256)
void conv_w(const float* __restrict__ W, _Float16* __restrict__ Wh, _Float16* __restrict__ Wl,
            int* __restrict__ cnt) {
    if (blockIdx.x == 0 && threadIdx.x == 0) *cnt = 0;
    int i = blockIdx.x * 256 + threadIdx.x;       // over 458752 float4s (exact)
    int f = i * 4;
    int e = f / DIM;
    int k = f - e * DIM;
    float4 v = ((const float4*)W)[i];
    v.x *= WSCALE; v.y *= WSCALE; v.z *= WSCALE; v.w *= WSCALE;
    half4v h, l;
    h[0] = hi16(v.x); l[0] = lo16(v.x);
    h[1] = hi16(v.y); l[1] = lo16(v.y);
    h[2] = hi16(v.z); l[2] = lo16(v.z);
    h[3] = hi16(v.w); l[3] = lo16(v.w);
    int o = ((k >> 5) << 13) + (e << 5) + (k & 31);   // chunk-major offset
    *(half4v*)(Wh + o) = h;
    *(half4v*)(Wl + o) = l;
}

// ---------------- asm pipeline primitives ----------------
#define MFMA16(a, b, c) __builtin_amdgcn_mfma_f32_16x16x32_f16(a, b, c, 0, 0, 0)

#define VWAIT(n) do { \
    asm volatile("s_waitcnt vmcnt(" #n ")" ::: "memory"); \
    __builtin_amdgcn_sched_barrier(0); \
} while (0)

// one W chunk (4 x dwordx4) into named set S; n=1 tile at +512 halves = +1024 B imm
#define ISSUE_WS(c, S) do { \
    const _Float16* _p = wph0 + (size_t)(c) * 8192; \
    const _Float16* _q = wpl0 + (size_t)(c) * 8192; \
    asm volatile("global_load_dwordx4 %0, %1, off"             : "=&v"(S##h0) : "v"(_p)); \
    asm volatile("global_load_dwordx4 %0, %1, off offset:1024" : "=&v"(S##h1) : "v"(_p)); \
    asm volatile("global_load_dwordx4 %0, %1, off"             : "=&v"(S##l0) : "v"(_q)); \
    asm volatile("global_load_dwordx4 %0, %1, off offset:1024" : "=&v"(S##l1) : "v"(_q)); \
} while (0)

// X for 2-chunk group gg: 8 floats per thread
#define ISSUE_X(gg) do { \
    const float* _px = xsrc + (size_t)(gg) * 64; \
    asm volatile("global_load_dwordx4 %0, %1, off"           : "=&v"(xa) : "v"(_px)); \
    asm volatile("global_load_dwordx4 %0, %1, off offset:16" : "=&v"(xb) : "v"(_px)); \
} while (0)

// A-frags from LDS + 12 MFMA (order identical to verified kernel)
#define COMPUTE(ABP, BH0, BH1, BL0, BL1) do { \
    const _Float16* _ab = (ABP); \
    half8 ah0 = *(const half8*)(_ab + abase0); \
    half8 ah1 = *(const half8*)(_ab + abase1); \
    half8 al0 = *(const half8*)(_ab + 2048 + abase0); \
    half8 al1 = *(const half8*)(_ab + 2048 + abase1); \
    __builtin_amdgcn_s_setprio(1); \
    acc00 = MFMA16(ah0, BH0, acc00); acc00 = MFMA16(ah0, BL0, acc00); acc00 = MFMA16(al0, BH0, acc00); \
    acc01 = MFMA16(ah0, BH1, acc01); acc01 = MFMA16(ah0, BL1, acc01); acc01 = MFMA16(al0, BH1, acc01); \
    acc10 = MFMA16(ah1, BH0, acc10); acc10 = MFMA16(ah1, BL0, acc10); acc10 = MFMA16(al1, BH0, acc10); \
    acc11 = MFMA16(ah1, BH1, acc11); acc11 = MFMA16(ah1, BL1, acc11); acc11 = MFMA16(al1, BH1, acc11); \
    __builtin_amdgcn_s_setprio(0); \
} while (0)

#define COMPUTE_S(ABP, S) COMPUTE(ABP, S##h0, S##h1, S##l0, S##l1)

#define DUMPF() do { \
    accf00 += acc00; acc00 = (f32x4)(0.0f); \
    accf01 += acc01; acc01 = (f32x4)(0.0f); \
    accf10 += acc10; acc10 = (f32x4)(0.0f); \
    accf11 += acc11; acc11 = (f32x4)(0.0f); \
} while (0)

#define CONVERT_WRITE_X(dstbuf) do { \
    half8 h8, l8; \
    const float v[8] = {xa.x, xa.y, xa.z, xa.w, xb.x, xb.y, xb.z, xb.w}; \
    _Pragma("unroll") \
    for (int e = 0; e < 8; ++e) { h8[e] = hi16(v[e]); l8[e] = lo16(v[e]); } \
    _Float16* d = hb + (dstbuf) * 8192 + xdst; \
    *(half8*)(d)        = h8; \
    *(half8*)(d + 2048) = l8; \
} while (0)

// ---------------- Kernel 1: fp16-split MFMA GEMM -> logits to global (unchanged from R4) ----------------
// 512 threads (8 waves), tile [64 tokens] x [128 experts], grid 512 = 2 barrier domains/CU.
// E-split: eh=(bid>>2)&1 -> all blocks of an XCD share one W-half (L2-resident).
// Per-(t,e) MFMA product order + accf dump cadence identical -> logits bit-identical.
__global__ __launch_bounds__(512, 4)
void gate_main(const float* __restrict__ X, const _Float16* __restrict__ Wh,
               const _Float16* __restrict__ Wl, float* __restrict__ LG) {
    __shared__ _Float16 hb[16384];                // 32 KB: X dbuf [2 buf][2 chunks][2 planes][64][32]

    const int tid  = threadIdx.x;
    const int lane = tid & 63;
    const int wid  = tid >> 6;                    // 0..7
    const int mq   = wid >> 2;                    // 0..1  (token half: 32 rows)
    const int ns   = wid & 3;                     // 0..3  (expert slice: 32 of 128)
    const int bid  = blockIdx.x;
    const int eh   = (bid >> 2) & 1;              // E-half: XCD 0-3 -> 0, 4-7 -> 1
    const int mt   = (bid >> 3) * 4 + (bid & 3);  // 0..255, each (mt,eh) exactly once
    const int m0   = mt * BM;
    const int fr   = lane & 15;
    const int fk   = lane >> 4;                   // 0..3

    const int xcc = tid >> 8;                     // 0..1
    const int xr  = (tid >> 2) & 63;              // 0..63
    const int xs  = tid & 3;                      // 0..3
    const float* xsrc = X + (size_t)(m0 + xr) * DIM + xcc * 32 + xs * 8;
    const int xdst = xcc * 4096 + xr * 32 + ((xs ^ ((xr >> 1) & 3)) << 3);

    const int row0 = mq * 32 + fr;
    const int row1 = row0 + 16;
    const int abase0 = row0 * 32 + ((fk ^ ((row0 >> 1) & 3)) << 3);
    const int abase1 = row1 * 32 + ((fk ^ ((row1 >> 1) & 3)) << 3);

    const int wro = ((eh * 128 + ns * 32 + fr) << 5) + fk * 8;
    const _Float16* wph0 = Wh + wro;
    const _Float16* wpl0 = Wl + wro;

    f32x4 acc00 = {}, acc01 = {}, acc10 = {}, acc11 = {};
    f32x4 accf00 = {}, accf01 = {}, accf10 = {}, accf11 = {};
    half8 S0h0, S0h1, S0l0, S0l1;
    half8 S1h0, S1h1, S1l0, S1l1;
    half8 S2h0, S2h1, S2l0, S2l1;
    half8 S3h0, S3h1, S3l0, S3l1;
    float4 xa, xb;

    {
        float4 pa = *(const float4*)(xsrc);
        float4 pb = *(const float4*)(xsrc + 4);
        half8 h8, l8;
        const float v[8] = {pa.x, pa.y, pa.z, pa.w, pb.x, pb.y, pb.z, pb.w};
        #pragma unroll
        for (int e = 0; e < 8; ++e) { h8[e] = hi16(v[e]); l8[e] = lo16(v[e]); }
        *(half8*)(hb + xdst)        = h8;
        *(half8*)(hb + xdst + 2048) = l8;
    }
    asm volatile("s_waitcnt vmcnt(0) lgkmcnt(0)" ::: "memory");
    __builtin_amdgcn_sched_barrier(0);
    ISSUE_WS(0, S0);
    ISSUE_WS(1, S1);
    __builtin_amdgcn_s_barrier();                 // buf0 visible; 8 W-loads in flight

    for (int k = 0; k < 55; ++k) {
        const int c4 = k * 4;
        VWAIT(4); ISSUE_WS(c4 + 2, S2); ISSUE_X(2 * k + 1); COMPUTE_S(hb,        S0);
        VWAIT(6); ISSUE_WS(c4 + 3, S3);                     COMPUTE_S(hb + 4096, S1);
        VWAIT(4); CONVERT_WRITE_X(1);
        asm volatile("s_waitcnt lgkmcnt(0)" ::: "memory");
        __builtin_amdgcn_s_barrier();
        VWAIT(4); ISSUE_WS(c4 + 4, S0); ISSUE_X(2 * k + 2); COMPUTE_S(hb + 8192,  S2);
        VWAIT(6); ISSUE_WS(c4 + 5, S1);                     COMPUTE_S(hb + 12288, S3);
        if ((k & 3) == 3) DUMPF();
        VWAIT(4); CONVERT_WRITE_X(0);
        asm volatile("s_waitcnt lgkmcnt(0)" ::: "memory");
        __builtin_amdgcn_s_barrier();
    }
    VWAIT(4); ISSUE_WS(222, S2); ISSUE_X(111); COMPUTE_S(hb,        S0);
    VWAIT(6); ISSUE_WS(223, S3);               COMPUTE_S(hb + 4096, S1);
    VWAIT(4); CONVERT_WRITE_X(1);
    asm volatile("s_waitcnt lgkmcnt(0)" ::: "memory");
    __builtin_amdgcn_s_barrier();
    VWAIT(4); COMPUTE_S(hb + 8192,  S2);
    VWAIT(0); COMPUTE_S(hb + 12288, S3);
    DUMPF();

    {
        f32x4 af[2][2] = {{accf00, accf01}, {accf10, accf11}};
        #pragma unroll
        for (int m = 0; m < 2; ++m)
            #pragma unroll
            for (int n = 0; n < 2; ++n)
                #pragma unroll
                for (int r = 0; r < 4; ++r) {
                    int t = m0 + mq * 32 + m * 16 + fk * 4 + r;
                    int e = eh * 128 + ns * 32 + n * 16 + fr;
                    LG[(size_t)t * 256 + e] = af[m][n][r] * WUNSCALE;
                }
    }
}

// ---------------- Kernel 1b: routing + margin flags ----------------
// 256 blocks; 256 threads stage 64 rotated rows (4x faster than R4's 64-thread staging)
// + Bp cached in LDS (kills the serial scalar-load chain in the 2300-iter scan).
// Routing math verbatim (bit-identical values).
__global__ __launch_bounds__(256)
void gate_route(const float* __restrict__ LG, const float* __restrict__ Bp,
                float* __restrict__ outw, float* __restrict__ outi,
                int* __restrict__ cnt, int* __restrict__ list) {
    __shared__ float lrow[64 * 256];              // 64 KB
    __shared__ float bph[256];
    const int tid = threadIdx.x;
    const int gt0 = blockIdx.x * 64;

    bph[tid] = Bp[tid];
    const int col = tid & 63;
    const int rq  = tid >> 6;                     // 0..3
    #pragma unroll 4
    for (int r0 = 0; r0 < 16; ++r0) {             // coalesced 1 KB/row, rotated scatter
        int r = r0 * 4 + rq;
        float4 v = ((const float4*)LG)[(size_t)(gt0 + r) * 64 + col];
        int e = col * 4;
        lrow[r * 256 + ((e + 0 + r) & 255)] = v.x;
        lrow[r * 256 + ((e + 1 + r) & 255)] = v.y;
        lrow[r * 256 + ((e + 2 + r) & 255)] = v.z;
        lrow[r * 256 + ((e + 3 + r) & 255)] = v.w;
    }
    __syncthreads();

    if (tid < 64) {
        const int t = tid;
        const int gtok = gt0 + t;
        float* row = lrow + t * 256;

        for (int e = 0; e < 256; ++e) {
            int a = (e + t) & 255;
            row[a] = 1.0f / (1.0f + expf(-row[a]));
        }
        float gs[8];
        #pragma unroll
        for (int g = 0; g < 8; ++g) {
            float m1 = -FLT_MAX, m2 = -FLT_MAX;
            for (int e = g * 32; e < g * 32 + 32; ++e) {
                float v = row[(e + t) & 255] + bph[e];
                if (v > m1) { m2 = m1; m1 = v; }
                else if (v > m2) { m2 = v; }
            }
            gs[g] = m1 + m2;
        }
        unsigned sel = 0;
        #pragma unroll
        for (int r = 0; r < 4; ++r) {
            float best = -FLT_MAX; int bg = 0;
            #pragma unroll
            for (int g = 0; g < 8; ++g)
                if (!((sel >> g) & 1) && gs[g] > best) { best = gs[g]; bg = g; }
            sel |= 1u << bg;
        }
        float selmin = FLT_MAX, unselmax = -FLT_MAX;
        #pragma unroll
        for (int g = 0; g < 8; ++g) {
            if ((sel >> g) & 1) selmin = fminf(selmin, gs[g]);
            else                unselmax = fmaxf(unselmax, gs[g]);
        }
        bool flag = (selmin - unselmax) < (2.0f * TAU);

        float pv = FLT_MAX; int pe = -1;
        float wv8[8]; int ie8[8]; float wsum = 0.f;
        for (int j = 0; j < 9; ++j) {
            float best = -FLT_MAX; int be = 0;
            for (int e = 0; e < 256; ++e) {
                float v = ((sel >> (e >> 5)) & 1) ? (row[(e + t) & 255] + bph[e]) : 0.0f;
                bool after = (v < pv) || (v == pv && e > pe);
                if (after && v > best) { best = v; be = e; }
            }
            if (j > 0) flag = flag || ((pv - best) < TAU);
            if (j < 8) {
                float ow = row[(be + t) & 255];
                wv8[j] = ow; ie8[j] = be; wsum += ow;
            }
            pv = best; pe = be;
        }
        if (flag) {
            int slot = atomicAdd(cnt, 1);
            list[slot] = gtok;
        }
        float scale = (float)ROUTE_SCALE / wsum;
        #pragma unroll
        for (int j = 0; j < 8; ++j) {
            outw[(size_t)gtok * 8 + j] = wv8[j] * scale;
            outi[(size_t)gtok * 8 + j] = (float)ie8[j];
        }
    }
}

// ---------------- Kernel 2: fp64 recheck of flagged tokens ----------------
// 1024 threads: ALL 256 experts concurrent (4 lanes/expert) -> 448 loads/thread
// (was 1792 over 32 serial expert-passes), unroll-4 for ILP. Bp cached in LDS for
// the serial routing tail. fp64 sum order changes only at ~1e-16 (irrelevant vs the
// TAU=6e-6 margins that flagged these tokens). Grid 512, one token per block.
__global__ __launch_bounds__(1024)
void gate_fix(const float* __restrict__ X, const float* __restrict__ W,
              const float* __restrict__ Bp, float* __restrict__ outw,
              float* __restrict__ outi, const int* __restrict__ cnt,
              const int* __restrict__ list) {
    __shared__ float  xrow[DIM];                  // 28 KB
    __shared__ double sig[NEXP];                  // 2 KB
    __shared__ float  bsh[NEXP];                  // 1 KB
    const int tid = threadIdx.x;
    const int e   = tid >> 2;                     // 0..255
    const int j   = tid & 3;                      // 0..3
    const int n   = *cnt;
    if (tid < NEXP) bsh[tid] = Bp[tid];

    for (int li = blockIdx.x; li < n; li += gridDim.x) {
        const int t = list[li];
        __syncthreads();                          // prior iteration fully done

        for (int i = tid * 4; i < DIM; i += 4096)
            *(float4*)(xrow + i) = *(const float4*)(X + (size_t)t * DIM + i);
        __syncthreads();

        const float* wrow = W + (size_t)e * DIM + j * 4;
        const float* xr   = xrow + j * 4;
        double s0 = 0, s1 = 0, s2 = 0, s3 = 0;
        #pragma unroll 4
        for (int c = 0; c < DIM / 16; ++c) {      // 448 iters, k = c*16 + j*4
            float4 w4 = *(const float4*)(wrow + c * 16);
            float4 x4 = *(const float4*)(xr + c * 16);
            s0 = fma((double)x4.x, (double)w4.x, s0);
            s1 = fma((double)x4.y, (double)w4.y, s1);
            s2 = fma((double)x4.z, (double)w4.z, s2);
            s3 = fma((double)x4.w, (double)w4.w, s3);
        }
        double d = (s0 + s1) + (s2 + s3);
        d += __shfl_xor(d, 1);                    // reduce over the 4 lanes of this expert
        d += __shfl_xor(d, 2);
        if (j == 0) sig[e] = 1.0 / (1.0 + exp(-d));
        __syncthreads();

        if (tid == 0) {
            const double* row = sig;
            double gs[8];
            #pragma unroll
            for (int g = 0; g < 8; ++g) {
                double m1 = -DBL_MAX, m2 = -DBL_MAX;
                for (int e2 = g * 32; e2 < g * 32 + 32; ++e2) {
                    double v = row[e2] + (double)bsh[e2];
                    if (v > m1) { m2 = m1; m1 = v; }
                    else if (v > m2) { m2 = v; }
                }
                gs[g] = m1 + m2;
            }
            unsigned sel = 0;
            #pragma unroll
            for (int r = 0; r < 4; ++r) {
                double best = -DBL_MAX; int bg = 0;
                #pragma unroll
                for (int g = 0; g < 8; ++g)
                    if (!((sel >> g) & 1) && gs[g] > best) { best = gs[g]; bg = g; }
                sel |= 1u << bg;
            }
            double pv = DBL_MAX; int pe = -1;
            double wv8[8]; int ie8[8]; double wsum = 0.0;
            #pragma unroll
            for (int jj = 0; jj < 8; ++jj) {
                double best = -DBL_MAX; int be = 0;
                for (int e2 = 0; e2 < 256; ++e2) {
                    double v = ((sel >> (e2 >> 5)) & 1) ? (row[e2] + (double)bsh[e2]) : 0.0;
                    bool after = (v < pv) || (v == pv && e2 > pe);
                    if (after && v > best) { best = v; be = e2; }
                }
                double ow = row[be];
                wv8[jj] = ow; ie8[jj] = be; wsum += ow;
                pv = best; pe = be;
            }
            #pragma unroll
            for (int jj = 0; jj < 8; ++jj) {
                outw[(size_t)t * 8 + jj] = (float)((wv8[jj] / wsum) * ROUTE_SCALE);
                outi[(size_t)t * 8 + jj] = (float)ie8[jj];
            }
        }
    }
}

extern "C" void kernel_launch(void* const* d_in, const int* in_sizes, int n_in,
                              void* d_out, int out_size, void* d_ws, size_t ws_size,
                              hipStream_t stream) {
    const float* X  = (const float*)d_in[0];
    const float* W  = (const float*)d_in[1];
    const float* Bp = (const float*)d_in[2];
    float* outw = (float*)d_out;
    float* outi = (float*)d_out + (size_t)TOKENS * 8;

    _Float16* Wh = (_Float16*)d_ws;                          // 3.67 MB (chunk-major)
    _Float16* Wl = Wh + WPLANE;                              // 3.67 MB (chunk-major)
    int* cnt  = (int*)(Wl + WPLANE);                         // 16 B slot
    int* list = (int*)((char*)cnt + 16);                     // 64 KB
    float* LG = (float*)(list + TOKENS);                     // 16.8 MB logits (16B-aligned)

    conv_w    <<<dim3(WPLANE / 1024), dim3(256),  0, stream>>>(W, Wh, Wl, cnt);
    gate_main <<<dim3(512),           dim3(512),  0, stream>>>(X, Wh, Wl, LG);
    gate_route<<<dim3(TOKENS / 64),   dim3(256),  0, stream>>>(LG, Bp, outw, outi, cnt, list);
    gate_fix  <<<dim3(512),           dim3(1024), 0, stream>>>(X, W, Bp, outw, outi, cnt, list);
}

// Round 6
// 761.132 us; speedup vs baseline: 1.4496x; 1.2438x over previous
//
#include <hip/hip_runtime.h>
#include <float.h>
#include <math.h>

#define TOKENS 16384
#define DIM    7168
#define NEXP   256
#define BM     64           // tokens per block
#define BK     32
#define NCHUNK (DIM / BK)   // 224
#define ROUTE_SCALE 2.5
#define TAU      6e-6f      // ~50x rms score error of the fp16-split path
#define WSCALE   1024.0f    // lifts W_lo out of fp16 denormal range (exact pow2)
#define WUNSCALE 0.0009765625f
#define FIXCAP   8192       // sig buffer aliases LG (16.8 MB = 8192*256 doubles)

typedef _Float16 half8  __attribute__((ext_vector_type(8)));
typedef _Float16 half4v __attribute__((ext_vector_type(4)));
typedef float    f32x4  __attribute__((ext_vector_type(4)));

#define WPLANE 1835008      // 256*7168 halves per plane

__device__ __forceinline__ _Float16 hi16(float f) { return (_Float16)f; }
__device__ __forceinline__ _Float16 lo16(float f) {
    _Float16 h = (_Float16)f;
    return (_Float16)(f - (float)h);
}

// ---------------- Kernel 0: split (W*1024) into fp16 hi/lo planes, CHUNK-MAJOR ----------------
__global__ __launch_bounds__(256)
void conv_w(const float* __restrict__ W, _Float16* __restrict__ Wh, _Float16* __restrict__ Wl,
            int* __restrict__ cnt) {
    if (blockIdx.x == 0 && threadIdx.x == 0) *cnt = 0;
    int i = blockIdx.x * 256 + threadIdx.x;       // over 458752 float4s (exact)
    int f = i * 4;
    int e = f / DIM;
    int k = f - e * DIM;
    float4 v = ((const float4*)W)[i];
    v.x *= WSCALE; v.y *= WSCALE; v.z *= WSCALE; v.w *= WSCALE;
    half4v h, l;
    h[0] = hi16(v.x); l[0] = lo16(v.x);
    h[1] = hi16(v.y); l[1] = lo16(v.y);
    h[2] = hi16(v.z); l[2] = lo16(v.z);
    h[3] = hi16(v.w); l[3] = lo16(v.w);
    int o = ((k >> 5) << 13) + (e << 5) + (k & 31);   // chunk-major offset
    *(half4v*)(Wh + o) = h;
    *(half4v*)(Wl + o) = l;
}

// ---------------- asm pipeline primitives ----------------
#define MFMA16(a, b, c) __builtin_amdgcn_mfma_f32_16x16x32_f16(a, b, c, 0, 0, 0)

#define VWAIT(n) do { \
    asm volatile("s_waitcnt vmcnt(" #n ")" ::: "memory"); \
    __builtin_amdgcn_sched_barrier(0); \
} while (0)

#define ISSUE_WS(c, S) do { \
    const _Float16* _p = wph0 + (size_t)(c) * 8192; \
    const _Float16* _q = wpl0 + (size_t)(c) * 8192; \
    asm volatile("global_load_dwordx4 %0, %1, off"             : "=&v"(S##h0) : "v"(_p)); \
    asm volatile("global_load_dwordx4 %0, %1, off offset:1024" : "=&v"(S##h1) : "v"(_p)); \
    asm volatile("global_load_dwordx4 %0, %1, off"             : "=&v"(S##l0) : "v"(_q)); \
    asm volatile("global_load_dwordx4 %0, %1, off offset:1024" : "=&v"(S##l1) : "v"(_q)); \
} while (0)

// X for 2-chunk group gg into a named float4 pair (issued one FULL group before use)
#define ISSUE_XP(gg, XA, XB) do { \
    const float* _px = xsrc + (size_t)(gg) * 64; \
    asm volatile("global_load_dwordx4 %0, %1, off"           : "=&v"(XA) : "v"(_px)); \
    asm volatile("global_load_dwordx4 %0, %1, off offset:16" : "=&v"(XB) : "v"(_px)); \
} while (0)

#define COMPUTE(ABP, BH0, BH1, BL0, BL1) do { \
    const _Float16* _ab = (ABP); \
    half8 ah0 = *(const half8*)(_ab + abase0); \
    half8 ah1 = *(const half8*)(_ab + abase1); \
    half8 al0 = *(const half8*)(_ab + 2048 + abase0); \
    half8 al1 = *(const half8*)(_ab + 2048 + abase1); \
    __builtin_amdgcn_s_setprio(1); \
    acc00 = MFMA16(ah0, BH0, acc00); acc00 = MFMA16(ah0, BL0, acc00); acc00 = MFMA16(al0, BH0, acc00); \
    acc01 = MFMA16(ah0, BH1, acc01); acc01 = MFMA16(ah0, BL1, acc01); acc01 = MFMA16(al0, BH1, acc01); \
    acc10 = MFMA16(ah1, BH0, acc10); acc10 = MFMA16(ah1, BL0, acc10); acc10 = MFMA16(al1, BH0, acc10); \
    acc11 = MFMA16(ah1, BH1, acc11); acc11 = MFMA16(ah1, BL1, acc11); acc11 = MFMA16(al1, BH1, acc11); \
    __builtin_amdgcn_s_setprio(0); \
} while (0)

#define COMPUTE_S(ABP, S) COMPUTE(ABP, S##h0, S##h1, S##l0, S##l1)

#define DUMPF() do { \
    accf00 += acc00; acc00 = (f32x4)(0.0f); \
    accf01 += acc01; acc01 = (f32x4)(0.0f); \
    accf10 += acc10; acc10 = (f32x4)(0.0f); \
    accf11 += acc11; acc11 = (f32x4)(0.0f); \
} while (0)

#define CONVERT_WRITE_XP(dstbuf, XA, XB) do { \
    half8 h8, l8; \
    const float v[8] = {XA.x, XA.y, XA.z, XA.w, XB.x, XB.y, XB.z, XB.w}; \
    _Pragma("unroll") \
    for (int e = 0; e < 8; ++e) { h8[e] = hi16(v[e]); l8[e] = lo16(v[e]); } \
    _Float16* d = hb + (dstbuf) * 8192 + xdst; \
    *(half8*)(d)        = h8; \
    *(half8*)(d + 2048) = l8; \
} while (0)

// ---------------- Kernel 1: fp16-split MFMA GEMM -> logits to global ----------------
// R5 structure (512 thr, 64x128 tile, grid 512, E-split L2-resident W) with ONE change:
// X is issued a FULL 2-chunk group ahead (2 register pairs A/B alternating), so the
// R5 third VWAIT(4) (which force-completed an X HBM load issued only ~1 chunk earlier,
// stalling all waves at every barrier) is GONE; X retires as a side effect of the
// group-top VWAIT(4) with ~4000 cyc of cover. W waits unchanged. MFMA order + accf
// dump cadence verbatim -> logits bit-identical.
__global__ __launch_bounds__(512, 4)
void gate_main(const float* __restrict__ X, const _Float16* __restrict__ Wh,
               const _Float16* __restrict__ Wl, float* __restrict__ LG) {
    __shared__ _Float16 hb[16384];                // 32 KB: X dbuf [2 buf][2 chunks][2 planes][64][32]

    const int tid  = threadIdx.x;
    const int lane = tid & 63;
    const int wid  = tid >> 6;                    // 0..7
    const int mq   = wid >> 2;                    // 0..1  (token half: 32 rows)
    const int ns   = wid & 3;                     // 0..3  (expert slice: 32 of 128)
    const int bid  = blockIdx.x;
    const int eh   = (bid >> 2) & 1;              // E-half: XCD 0-3 -> 0, 4-7 -> 1
    const int mt   = (bid >> 3) * 4 + (bid & 3);  // 0..255, each (mt,eh) exactly once
    const int m0   = mt * BM;
    const int fr   = lane & 15;
    const int fk   = lane >> 4;                   // 0..3

    const int xcc = tid >> 8;                     // 0..1
    const int xr  = (tid >> 2) & 63;              // 0..63
    const int xs  = tid & 3;                      // 0..3
    const float* xsrc = X + (size_t)(m0 + xr) * DIM + xcc * 32 + xs * 8;
    const int xdst = xcc * 4096 + xr * 32 + ((xs ^ ((xr >> 1) & 3)) << 3);

    const int row0 = mq * 32 + fr;
    const int row1 = row0 + 16;
    const int abase0 = row0 * 32 + ((fk ^ ((row0 >> 1) & 3)) << 3);
    const int abase1 = row1 * 32 + ((fk ^ ((row1 >> 1) & 3)) << 3);

    const int wro = ((eh * 128 + ns * 32 + fr) << 5) + fk * 8;
    const _Float16* wph0 = Wh + wro;
    const _Float16* wpl0 = Wl + wro;

    f32x4 acc00 = {}, acc01 = {}, acc10 = {}, acc11 = {};
    f32x4 accf00 = {}, accf01 = {}, accf10 = {}, accf11 = {};
    half8 S0h0, S0h1, S0l0, S0l1;
    half8 S1h0, S1h1, S1l0, S1l1;
    half8 S2h0, S2h1, S2l0, S2l1;
    half8 S3h0, S3h1, S3l0, S3l1;
    float4 xa, xb;                                // X pair A (even-group issues: X(2k+2))
    float4 xc, xd;                                // X pair B (odd-group issues: X(2k+3))

    // ---- prologue: stage X(0) plain; drain; issue X(1)->B, W(0)->S0, W(1)->S1 ----
    {
        float4 pa = *(const float4*)(xsrc);
        float4 pb = *(const float4*)(xsrc + 4);
        half8 h8, l8;
        const float v[8] = {pa.x, pa.y, pa.z, pa.w, pb.x, pb.y, pb.z, pb.w};
        #pragma unroll
        for (int e = 0; e < 8; ++e) { h8[e] = hi16(v[e]); l8[e] = lo16(v[e]); }
        *(half8*)(hb + xdst)        = h8;
        *(half8*)(hb + xdst + 2048) = l8;
    }
    asm volatile("s_waitcnt vmcnt(0) lgkmcnt(0)" ::: "memory");
    __builtin_amdgcn_sched_barrier(0);
    ISSUE_XP(1, xc, xd);
    ISSUE_WS(0, S0);
    ISSUE_WS(1, S1);
    __builtin_amdgcn_s_barrier();                 // steady invariant: [Xb(2), S0(4), S1(4)]

    for (int k = 0; k < 55; ++k) {
        const int c4 = k * 4;
        // even group 2k (buf0): chunks 4k,4k+1; VWAIT(4) retires X(2k+1)+W(4k)
        VWAIT(4); ISSUE_XP(2 * k + 2, xa, xb); ISSUE_WS(c4 + 2, S2); COMPUTE_S(hb,        S0);
        VWAIT(6); ISSUE_WS(c4 + 3, S3);                              COMPUTE_S(hb + 4096, S1);
        CONVERT_WRITE_XP(1, xc, xd);              // X(2k+1), retired at group-top VWAIT
        asm volatile("s_waitcnt lgkmcnt(0)" ::: "memory");
        __builtin_amdgcn_s_barrier();
        // odd group 2k+1 (buf1): chunks 4k+2,4k+3; VWAIT(4) retires X(2k+2)+W(4k+2)
        VWAIT(4); ISSUE_XP(2 * k + 3, xc, xd); ISSUE_WS(c4 + 4, S0); COMPUTE_S(hb + 8192,  S2);
        VWAIT(6); ISSUE_WS(c4 + 5, S1);                              COMPUTE_S(hb + 12288, S3);
        if ((k & 3) == 3) DUMPF();                // every 16 chunks: same cadence as verified
        CONVERT_WRITE_XP(0, xa, xb);              // X(2k+2)
        asm volatile("s_waitcnt lgkmcnt(0)" ::: "memory");
        __builtin_amdgcn_s_barrier();
    }
    // group 110 (buf0): chunks 220,221; queue [X(111), W220, W221]
    VWAIT(4); ISSUE_WS(222, S2); COMPUTE_S(hb,        S0);   // retires X(111)+W220
    VWAIT(4); ISSUE_WS(223, S3); COMPUTE_S(hb + 4096, S1);   // retires W221
    CONVERT_WRITE_XP(1, xc, xd);                  // X(111)
    asm volatile("s_waitcnt lgkmcnt(0)" ::: "memory");
    __builtin_amdgcn_s_barrier();
    // group 111 (buf1): chunks 222,223
    VWAIT(4); COMPUTE_S(hb + 8192,  S2);
    VWAIT(0); COMPUTE_S(hb + 12288, S3);
    DUMPF();                                      // chunk 223 -> final dump, same cadence

    {
        f32x4 af[2][2] = {{accf00, accf01}, {accf10, accf11}};
        #pragma unroll
        for (int m = 0; m < 2; ++m)
            #pragma unroll
            for (int n = 0; n < 2; ++n)
                #pragma unroll
                for (int r = 0; r < 4; ++r) {
                    int t = m0 + mq * 32 + m * 16 + fk * 4 + r;
                    int e = eh * 128 + ns * 32 + n * 16 + fr;
                    LG[(size_t)t * 256 + e] = af[m][n][r] * WUNSCALE;
                }
    }
}

// ---------------- Kernel 1b: routing + margin flags (BRANCHLESS scans) ----------------
// R5's serial scans cost ~240 cyc/iter: divergent if/else bodies forced exec-mask
// branches, so each LDS read sat single-outstanding (~120 cyc) on the critical path.
// Branchless (fmax/fmin + cndmask) bodies compute IDENTICAL values and let the LDS
// reads pipeline at throughput (~6 cyc). All selected indices/weights bit-identical.
__global__ __launch_bounds__(256)
void gate_route(const float* __restrict__ LG, const float* __restrict__ Bp,
                float* __restrict__ outw, float* __restrict__ outi,
                int* __restrict__ cnt, int* __restrict__ list) {
    __shared__ float lrow[64 * 256];              // 64 KB
    __shared__ float bph[256];
    const int tid = threadIdx.x;
    const int gt0 = blockIdx.x * 64;

    bph[tid] = Bp[tid];
    const int col = tid & 63;
    const int rq  = tid >> 6;                     // 0..3
    #pragma unroll 4
    for (int r0 = 0; r0 < 16; ++r0) {             // coalesced 1 KB/row, rotated scatter
        int r = r0 * 4 + rq;
        float4 v = ((const float4*)LG)[(size_t)(gt0 + r) * 64 + col];
        int e = col * 4;
        lrow[r * 256 + ((e + 0 + r) & 255)] = v.x;
        lrow[r * 256 + ((e + 1 + r) & 255)] = v.y;
        lrow[r * 256 + ((e + 2 + r) & 255)] = v.z;
        lrow[r * 256 + ((e + 3 + r) & 255)] = v.w;
    }
    __syncthreads();

    if (tid < 64) {
        const int t = tid;
        const int gtok = gt0 + t;
        float* row = lrow + t * 256;

        #pragma unroll 4
        for (int e = 0; e < 256; ++e) {
            int a = (e + t) & 255;
            row[a] = 1.0f / (1.0f + expf(-row[a]));
        }
        float gs[8];
        #pragma unroll
        for (int g = 0; g < 8; ++g) {
            float m1 = -FLT_MAX, m2 = -FLT_MAX;
            #pragma unroll 8
            for (int e = g * 32; e < g * 32 + 32; ++e) {
                float v = row[(e + t) & 255] + bph[e];
                m2 = fmaxf(m2, fminf(m1, v));     // exact branchless top-2 update
                m1 = fmaxf(m1, v);
            }
            gs[g] = m1 + m2;
        }
        unsigned sel = 0;
        #pragma unroll
        for (int r = 0; r < 4; ++r) {
            float best = -FLT_MAX; int bg = 0;
            #pragma unroll
            for (int g = 0; g < 8; ++g) {
                int ok = (((sel >> g) & 1) == 0) & (gs[g] > best);
                best = ok ? gs[g] : best;
                bg   = ok ? g : bg;
            }
            sel |= 1u << bg;
        }
        float selmin = FLT_MAX, unselmax = -FLT_MAX;
        #pragma unroll
        for (int g = 0; g < 8; ++g) {
            int s = (sel >> g) & 1;
            selmin   = s ? fminf(selmin, gs[g])   : selmin;
            unselmax = s ? unselmax : fmaxf(unselmax, gs[g]);
        }
        bool flag = (selmin - unselmax) < (2.0f * TAU);

        float pv = FLT_MAX; int pe = -1;
        float wv8[8]; int ie8[8]; float wsum = 0.f;
        for (int j = 0; j < 9; ++j) {
            float best = -FLT_MAX; int be = 0;
            #pragma unroll 8
            for (int e = 0; e < 256; ++e) {
                float vr = row[(e + t) & 255] + bph[e];          // unconditional LDS read
                float v  = ((sel >> (e >> 5)) & 1) ? vr : 0.0f;
                int after = (v < pv) | ((v == pv) & (e > pe));
                int take  = after & (v > best);
                best = take ? v : best;
                be   = take ? e : be;
            }
            if (j > 0) flag = flag || ((pv - best) < TAU);
            if (j < 8) {
                float ow = row[(be + t) & 255];
                wv8[j] = ow; ie8[j] = be; wsum += ow;
            }
            pv = best; pe = be;
        }
        if (flag) {
            int slot = atomicAdd(cnt, 1);
            list[slot] = gtok;
        }
        float scale = (float)ROUTE_SCALE / wsum;
        #pragma unroll
        for (int j = 0; j < 8; ++j) {
            outw[(size_t)gtok * 8 + j] = wv8[j] * scale;
            outi[(size_t)gtok * 8 + j] = (float)ie8[j];
        }
    }
}

// ---------------- Kernel 2a: fp64 dots for flagged tokens, SHARED W ----------------
// 256 blocks = 32 expert-octets x 8 token-stripes. s = bid&31 puts all 8 stripe-blocks
// of an octet on ONE XCD (bids congruent mod 8) -> 229 KB W slice is L2-resident,
// total W traffic ~59 MB instead of R5's 807 MB (7.34 MB per token-block).
// Coalesced 64-lane dots (256 B/wave-instr), 4 fp64 accumulators for ILP.
// sig aliases the LG buffer (gate_route has fully consumed LG; stream-ordered).
__global__ __launch_bounds__(256)
void gate_fix_dot(const float* __restrict__ X, const float* __restrict__ W,
                  const int* __restrict__ cnt, const int* __restrict__ list,
                  double* __restrict__ sig) {
    __shared__ float xrow[DIM];                   // 28 KB
    const int tid  = threadIdx.x;
    const int lane = tid & 63;
    const int wv   = tid >> 6;                    // 0..3
    const int s    = blockIdx.x & 31;             // expert octet
    const int r    = blockIdx.x >> 5;             // token stripe 0..7
    int n = *cnt; if (n > FIXCAP) n = FIXCAP;

    for (int li = r; li < n; li += 8) {
        const int t = list[li];
        __syncthreads();                          // prior token's xrow readers done
        for (int i = tid * 4; i < DIM; i += 1024)
            *(float4*)(xrow + i) = *(const float4*)(X + (size_t)t * DIM + i);
        __syncthreads();

        #pragma unroll
        for (int ee = 0; ee < 2; ++ee) {
            const int e = s * 8 + wv * 2 + ee;
            const float* wr = W + (size_t)e * DIM + lane;
            const float* xr = xrow + lane;
            double d0 = 0, d1 = 0, d2 = 0, d3 = 0;
            for (int kk = 0; kk < DIM / 256; ++kk) {      // 28 iters, 4-deep ILP
                int k = kk * 256;
                d0 = fma((double)xr[k],       (double)wr[k],       d0);
                d1 = fma((double)xr[k + 64],  (double)wr[k + 64],  d1);
                d2 = fma((double)xr[k + 128], (double)wr[k + 128], d2);
                d3 = fma((double)xr[k + 192], (double)wr[k + 192], d3);
            }
            double d = (d0 + d1) + (d2 + d3);
            #pragma unroll
            for (int m = 1; m <= 32; m <<= 1)
                d += __shfl_xor(d, m);
            if (lane == 0) sig[(size_t)li * 256 + e] = 1.0 / (1.0 + exp(-d));
        }
    }
}

// ---------------- Kernel 2b: fp64 routing for flagged tokens (branchless, LDS-staged) ----------------
__global__ __launch_bounds__(64)
void gate_fix_route(const float* __restrict__ Bp, float* __restrict__ outw,
                    float* __restrict__ outi, const int* __restrict__ cnt,
                    const int* __restrict__ list, const double* __restrict__ sig) {
    __shared__ double srow[NEXP];                 // 2 KB
    __shared__ double bsd[NEXP];                  // 2 KB
    const int tid = threadIdx.x;
    int n = *cnt; if (n > FIXCAP) n = FIXCAP;
    #pragma unroll
    for (int i = tid; i < NEXP; i += 64) bsd[i] = (double)Bp[i];

    for (int li = blockIdx.x; li < n; li += 256) {
        __syncthreads();
        #pragma unroll
        for (int i = tid; i < NEXP; i += 64) srow[i] = sig[(size_t)li * 256 + i];
        __syncthreads();

        if (tid == 0) {
            const int t = list[li];
            double gs[8];
            #pragma unroll
            for (int g = 0; g < 8; ++g) {
                double m1 = -DBL_MAX, m2 = -DBL_MAX;
                #pragma unroll 8
                for (int e = g * 32; e < g * 32 + 32; ++e) {
                    double v = srow[e] + bsd[e];
                    m2 = fmax(m2, fmin(m1, v));
                    m1 = fmax(m1, v);
                }
                gs[g] = m1 + m2;
            }
            unsigned sel = 0;
            #pragma unroll
            for (int r = 0; r < 4; ++r) {
                double best = -DBL_MAX; int bg = 0;
                #pragma unroll
                for (int g = 0; g < 8; ++g) {
                    int ok = (((sel >> g) & 1) == 0) & (gs[g] > best);
                    best = ok ? gs[g] : best;
                    bg   = ok ? g : bg;
                }
                sel |= 1u << bg;
            }
            double pv = DBL_MAX; int pe = -1;
            double wv8[8]; int ie8[8]; double wsum = 0.0;
            #pragma unroll
            for (int j = 0; j < 8; ++j) {
                double best = -DBL_MAX; int be = 0;
                #pragma unroll 8
                for (int e = 0; e < 256; ++e) {
                    double vr = srow[e] + bsd[e];
                    double v  = ((sel >> (e >> 5)) & 1) ? vr : 0.0;
                    int after = (v < pv) | ((v == pv) & (e > pe));
                    int take  = after & (v > best);
                    best = take ? v : best;
                    be   = take ? e : be;
                }
                double ow = srow[be];
                wv8[j] = ow; ie8[j] = be; wsum += ow;
                pv = best; pe = be;
            }
            #pragma unroll
            for (int j = 0; j < 8; ++j) {
                outw[(size_t)t * 8 + j] = (float)((wv8[j] / wsum) * ROUTE_SCALE);
                outi[(size_t)t * 8 + j] = (float)ie8[j];
            }
        }
    }
}

extern "C" void kernel_launch(void* const* d_in, const int* in_sizes, int n_in,
                              void* d_out, int out_size, void* d_ws, size_t ws_size,
                              hipStream_t stream) {
    const float* X  = (const float*)d_in[0];
    const float* W  = (const float*)d_in[1];
    const float* Bp = (const float*)d_in[2];
    float* outw = (float*)d_out;
    float* outi = (float*)d_out + (size_t)TOKENS * 8;

    _Float16* Wh = (_Float16*)d_ws;                          // 3.67 MB (chunk-major)
    _Float16* Wl = Wh + WPLANE;                              // 3.67 MB (chunk-major)
    int* cnt  = (int*)(Wl + WPLANE);                         // 16 B slot
    int* list = (int*)((char*)cnt + 16);                     // 64 KB
    float* LG = (float*)(list + TOKENS);                     // 16.8 MB logits
    double* sig = (double*)LG;                               // alias: route consumed LG first

    conv_w        <<<dim3(WPLANE / 1024), dim3(256), 0, stream>>>(W, Wh, Wl, cnt);
    gate_main     <<<dim3(512),           dim3(512), 0, stream>>>(X, Wh, Wl, LG);
    gate_route    <<<dim3(TOKENS / 64),   dim3(256), 0, stream>>>(LG, Bp, outw, outi, cnt, list);
    gate_fix_dot  <<<dim3(256),           dim3(256), 0, stream>>>(X, W, cnt, list, sig);
    gate_fix_route<<<dim3(256),           dim3(64),  0, stream>>>(Bp, outw, outi, cnt, list, sig);
}

// Round 7
// 480.541 us; speedup vs baseline: 2.2960x; 1.5839x over previous
//
#include <hip/hip_runtime.h>
#include <float.h>
#include <math.h>

#define TOKENS 16384
#define DIM    7168
#define NEXP   256
#define BM     64           // tokens per block
#define BK     32
#define NCHUNK (DIM / BK)   // 224
#define ROUTE_SCALE 2.5
#define TAU      6e-6f      // ~50x rms score error of the fp16-split path
#define WSCALE   1024.0f    // lifts W_lo out of fp16 denormal range (exact pow2)
#define WUNSCALE 0.0009765625f
#define FIXCAP   8192       // sig buffer aliases LG (16.8 MB = 8192*256 doubles)

typedef _Float16 half8  __attribute__((ext_vector_type(8)));
typedef _Float16 half4v __attribute__((ext_vector_type(4)));
typedef float    f32x4  __attribute__((ext_vector_type(4)));

#define WPLANE 1835008      // 256*7168 halves per plane

__device__ __forceinline__ _Float16 hi16(float f) { return (_Float16)f; }
__device__ __forceinline__ _Float16 lo16(float f) {
    _Float16 h = (_Float16)f;
    return (_Float16)(f - (float)h);
}

// ---------------- Kernel 0: split (W*1024) into fp16 hi/lo planes, CHUNK-MAJOR ----------------
__global__ __launch_bounds__(256)
void conv_w(const float* __restrict__ W, _Float16* __restrict__ Wh, _Float16* __restrict__ Wl,
            int* __restrict__ cnt) {
    if (blockIdx.x == 0 && threadIdx.x == 0) *cnt = 0;
    int i = blockIdx.x * 256 + threadIdx.x;       // over 458752 float4s (exact)
    int f = i * 4;
    int e = f / DIM;
    int k = f - e * DIM;
    float4 v = ((const float4*)W)[i];
    v.x *= WSCALE; v.y *= WSCALE; v.z *= WSCALE; v.w *= WSCALE;
    half4v h, l;
    h[0] = hi16(v.x); l[0] = lo16(v.x);
    h[1] = hi16(v.y); l[1] = lo16(v.y);
    h[2] = hi16(v.z); l[2] = lo16(v.z);
    h[3] = hi16(v.w); l[3] = lo16(v.w);
    int o = ((k >> 5) << 13) + (e << 5) + (k & 31);   // chunk-major offset
    *(half4v*)(Wh + o) = h;
    *(half4v*)(Wl + o) = l;
}

// ---------------- asm pipeline primitives ----------------
#define MFMA16(a, b, c) __builtin_amdgcn_mfma_f32_16x16x32_f16(a, b, c, 0, 0, 0)

#define VWAIT(n) do { \
    asm volatile("s_waitcnt vmcnt(" #n ")" ::: "memory"); \
    __builtin_amdgcn_sched_barrier(0); \
} while (0)

#define ISSUE_WS(c, S) do { \
    const _Float16* _p = wph0 + (size_t)(c) * 8192; \
    const _Float16* _q = wpl0 + (size_t)(c) * 8192; \
    asm volatile("global_load_dwordx4 %0, %1, off"             : "=&v"(S##h0) : "v"(_p)); \
    asm volatile("global_load_dwordx4 %0, %1, off offset:1024" : "=&v"(S##h1) : "v"(_p)); \
    asm volatile("global_load_dwordx4 %0, %1, off"             : "=&v"(S##l0) : "v"(_q)); \
    asm volatile("global_load_dwordx4 %0, %1, off offset:1024" : "=&v"(S##l1) : "v"(_q)); \
} while (0)

#define ISSUE_XP(gg, XA, XB) do { \
    const float* _px = xsrc + (size_t)(gg) * 64; \
    asm volatile("global_load_dwordx4 %0, %1, off"           : "=&v"(XA) : "v"(_px)); \
    asm volatile("global_load_dwordx4 %0, %1, off offset:16" : "=&v"(XB) : "v"(_px)); \
} while (0)

#define COMPUTE(ABP, BH0, BH1, BL0, BL1) do { \
    const _Float16* _ab = (ABP); \
    half8 ah0 = *(const half8*)(_ab + abase0); \
    half8 ah1 = *(const half8*)(_ab + abase1); \
    half8 al0 = *(const half8*)(_ab + 2048 + abase0); \
    half8 al1 = *(const half8*)(_ab + 2048 + abase1); \
    __builtin_amdgcn_s_setprio(1); \
    acc00 = MFMA16(ah0, BH0, acc00); acc00 = MFMA16(ah0, BL0, acc00); acc00 = MFMA16(al0, BH0, acc00); \
    acc01 = MFMA16(ah0, BH1, acc01); acc01 = MFMA16(ah0, BL1, acc01); acc01 = MFMA16(al0, BH1, acc01); \
    acc10 = MFMA16(ah1, BH0, acc10); acc10 = MFMA16(ah1, BL0, acc10); acc10 = MFMA16(al1, BH0, acc10); \
    acc11 = MFMA16(ah1, BH1, acc11); acc11 = MFMA16(ah1, BL1, acc11); acc11 = MFMA16(al1, BH1, acc11); \
    __builtin_amdgcn_s_setprio(0); \
} while (0)

#define COMPUTE_S(ABP, S) COMPUTE(ABP, S##h0, S##h1, S##l0, S##l1)

#define DUMPF() do { \
    accf00 += acc00; acc00 = (f32x4)(0.0f); \
    accf01 += acc01; acc01 = (f32x4)(0.0f); \
    accf10 += acc10; acc10 = (f32x4)(0.0f); \
    accf11 += acc11; acc11 = (f32x4)(0.0f); \
} while (0)

#define CONVERT_WRITE_XP(dstbuf, XA, XB) do { \
    half8 h8, l8; \
    const float v[8] = {XA.x, XA.y, XA.z, XA.w, XB.x, XB.y, XB.z, XB.w}; \
    _Pragma("unroll") \
    for (int e = 0; e < 8; ++e) { h8[e] = hi16(v[e]); l8[e] = lo16(v[e]); } \
    _Float16* d = hb + (dstbuf) * 8192 + xdst; \
    *(half8*)(d)        = h8; \
    *(half8*)(d + 2048) = l8; \
} while (0)

// ---------------- Kernel 1: fp16-split MFMA GEMM -> logits to global (byte-identical to R6) ----------------
__global__ __launch_bounds__(512, 4)
void gate_main(const float* __restrict__ X, const _Float16* __restrict__ Wh,
               const _Float16* __restrict__ Wl, float* __restrict__ LG) {
    __shared__ _Float16 hb[16384];                // 32 KB: X dbuf [2 buf][2 chunks][2 planes][64][32]

    const int tid  = threadIdx.x;
    const int lane = tid & 63;
    const int wid  = tid >> 6;                    // 0..7
    const int mq   = wid >> 2;                    // 0..1  (token half: 32 rows)
    const int ns   = wid & 3;                     // 0..3  (expert slice: 32 of 128)
    const int bid  = blockIdx.x;
    const int eh   = (bid >> 2) & 1;              // E-half: XCD 0-3 -> 0, 4-7 -> 1
    const int mt   = (bid >> 3) * 4 + (bid & 3);  // 0..255, each (mt,eh) exactly once
    const int m0   = mt * BM;
    const int fr   = lane & 15;
    const int fk   = lane >> 4;                   // 0..3

    const int xcc = tid >> 8;                     // 0..1
    const int xr  = (tid >> 2) & 63;              // 0..63
    const int xs  = tid & 3;                      // 0..3
    const float* xsrc = X + (size_t)(m0 + xr) * DIM + xcc * 32 + xs * 8;
    const int xdst = xcc * 4096 + xr * 32 + ((xs ^ ((xr >> 1) & 3)) << 3);

    const int row0 = mq * 32 + fr;
    const int row1 = row0 + 16;
    const int abase0 = row0 * 32 + ((fk ^ ((row0 >> 1) & 3)) << 3);
    const int abase1 = row1 * 32 + ((fk ^ ((row1 >> 1) & 3)) << 3);

    const int wro = ((eh * 128 + ns * 32 + fr) << 5) + fk * 8;
    const _Float16* wph0 = Wh + wro;
    const _Float16* wpl0 = Wl + wro;

    f32x4 acc00 = {}, acc01 = {}, acc10 = {}, acc11 = {};
    f32x4 accf00 = {}, accf01 = {}, accf10 = {}, accf11 = {};
    half8 S0h0, S0h1, S0l0, S0l1;
    half8 S1h0, S1h1, S1l0, S1l1;
    half8 S2h0, S2h1, S2l0, S2l1;
    half8 S3h0, S3h1, S3l0, S3l1;
    float4 xa, xb;                                // X pair A
    float4 xc, xd;                                // X pair B

    {
        float4 pa = *(const float4*)(xsrc);
        float4 pb = *(const float4*)(xsrc + 4);
        half8 h8, l8;
        const float v[8] = {pa.x, pa.y, pa.z, pa.w, pb.x, pb.y, pb.z, pb.w};
        #pragma unroll
        for (int e = 0; e < 8; ++e) { h8[e] = hi16(v[e]); l8[e] = lo16(v[e]); }
        *(half8*)(hb + xdst)        = h8;
        *(half8*)(hb + xdst + 2048) = l8;
    }
    asm volatile("s_waitcnt vmcnt(0) lgkmcnt(0)" ::: "memory");
    __builtin_amdgcn_sched_barrier(0);
    ISSUE_XP(1, xc, xd);
    ISSUE_WS(0, S0);
    ISSUE_WS(1, S1);
    __builtin_amdgcn_s_barrier();                 // steady invariant: [Xb(2), S0(4), S1(4)]

    for (int k = 0; k < 55; ++k) {
        const int c4 = k * 4;
        VWAIT(4); ISSUE_XP(2 * k + 2, xa, xb); ISSUE_WS(c4 + 2, S2); COMPUTE_S(hb,        S0);
        VWAIT(6); ISSUE_WS(c4 + 3, S3);                              COMPUTE_S(hb + 4096, S1);
        CONVERT_WRITE_XP(1, xc, xd);
        asm volatile("s_waitcnt lgkmcnt(0)" ::: "memory");
        __builtin_amdgcn_s_barrier();
        VWAIT(4); ISSUE_XP(2 * k + 3, xc, xd); ISSUE_WS(c4 + 4, S0); COMPUTE_S(hb + 8192,  S2);
        VWAIT(6); ISSUE_WS(c4 + 5, S1);                              COMPUTE_S(hb + 12288, S3);
        if ((k & 3) == 3) DUMPF();
        CONVERT_WRITE_XP(0, xa, xb);
        asm volatile("s_waitcnt lgkmcnt(0)" ::: "memory");
        __builtin_amdgcn_s_barrier();
    }
    VWAIT(4); ISSUE_WS(222, S2); COMPUTE_S(hb,        S0);
    VWAIT(4); ISSUE_WS(223, S3); COMPUTE_S(hb + 4096, S1);
    CONVERT_WRITE_XP(1, xc, xd);
    asm volatile("s_waitcnt lgkmcnt(0)" ::: "memory");
    __builtin_amdgcn_s_barrier();
    VWAIT(4); COMPUTE_S(hb + 8192,  S2);
    VWAIT(0); COMPUTE_S(hb + 12288, S3);
    DUMPF();

    {
        f32x4 af[2][2] = {{accf00, accf01}, {accf10, accf11}};
        #pragma unroll
        for (int m = 0; m < 2; ++m)
            #pragma unroll
            for (int n = 0; n < 2; ++n)
                #pragma unroll
                for (int r = 0; r < 4; ++r) {
                    int t = m0 + mq * 32 + m * 16 + fk * 4 + r;
                    int e = eh * 128 + ns * 32 + n * 16 + fr;
                    LG[(size_t)t * 256 + e] = af[m][n][r] * WUNSCALE;
                }
    }
}

// ---------------- Kernel 1b: routing + margin flags — ONE WAVE PER TOKEN, no LDS ----------------
// lane l owns experts 4l..4l+3 (coalesced float4 from LG and Bp). Group top-2 via exact
// per-lane top-2 + 3-step shfl_xor set-merge (order-independent -> gs bit-identical);
// top-4 groups + flag run redundantly per lane on gathered gs[8] (verbatim serial code);
// 9-pass top-scan = per-lane ascending strict-> local scan + 64-lane argmax butterfly with
// comparator (greater) OR (equal AND smaller index) == serial leftmost-maximum. All
// selections, weights, flags bit-identical to the R6-verified serial path.
__global__ __launch_bounds__(1024)
void gate_route(const float* __restrict__ LG, const float* __restrict__ Bp,
                float* __restrict__ outw, float* __restrict__ outi,
                int* __restrict__ cnt, int* __restrict__ list) {
    const int lane = threadIdx.x & 63;
    const int wv   = threadIdx.x >> 6;            // 0..15
    const int nw   = gridDim.x * 16;              // total waves
    const int e0   = lane * 4;

    const float4 b4 = ((const float4*)Bp)[lane];  // bias for experts e0..e0+3

    for (int t = blockIdx.x * 16 + wv; t < TOKENS; t += nw) {
        float4 v4 = ((const float4*)LG)[(size_t)t * 64 + lane];
        const float s0 = 1.0f / (1.0f + expf(-v4.x));
        const float s1 = 1.0f / (1.0f + expf(-v4.y));
        const float s2 = 1.0f / (1.0f + expf(-v4.z));
        const float s3 = 1.0f / (1.0f + expf(-v4.w));
        const float c0 = s0 + b4.x, c1 = s1 + b4.y, c2 = s2 + b4.z, c3 = s3 + b4.w;

        // ---- group scores: exact top-2, local then 8-lane merge ----
        float m1 = -FLT_MAX, m2 = -FLT_MAX;
        m2 = fmaxf(m2, fminf(m1, c0)); m1 = fmaxf(m1, c0);
        m2 = fmaxf(m2, fminf(m1, c1)); m1 = fmaxf(m1, c1);
        m2 = fmaxf(m2, fminf(m1, c2)); m1 = fmaxf(m1, c2);
        m2 = fmaxf(m2, fminf(m1, c3)); m1 = fmaxf(m1, c3);
        #pragma unroll
        for (int m = 1; m < 8; m <<= 1) {         // xor 1,2,4 stays within the 8-lane group
            float o1 = __shfl_xor(m1, m);
            float o2 = __shfl_xor(m2, m);
            float hi = fmaxf(m1, o1);
            float lo = fmaxf(fminf(m1, o1), fmaxf(m2, o2));
            m1 = hi; m2 = lo;
        }
        const float gsl = m1 + m2;
        float gs[8];
        #pragma unroll
        for (int j = 0; j < 8; ++j) gs[j] = __shfl(gsl, j * 8);

        // ---- top-4 groups (verbatim serial, redundant per lane) ----
        unsigned sel = 0;
        #pragma unroll
        for (int r = 0; r < 4; ++r) {
            float best = -FLT_MAX; int bg = 0;
            #pragma unroll
            for (int g = 0; g < 8; ++g) {
                int ok = (((sel >> g) & 1) == 0) & (gs[g] > best);
                best = ok ? gs[g] : best;
                bg   = ok ? g : bg;
            }
            sel |= 1u << bg;
        }
        float selmin = FLT_MAX, unselmax = -FLT_MAX;
        #pragma unroll
        for (int g = 0; g < 8; ++g) {
            int s = (sel >> g) & 1;
            selmin   = s ? fminf(selmin, gs[g])   : selmin;
            unselmax = s ? unselmax : fmaxf(unselmax, gs[g]);
        }
        bool flag = (selmin - unselmax) < (2.0f * TAU);

        // ---- masked candidate values (this lane's group is lane>>3) ----
        const int gsel = (sel >> (lane >> 3)) & 1;
        const float z0 = gsel ? c0 : 0.0f;
        const float z1 = gsel ? c1 : 0.0f;
        const float z2 = gsel ? c2 : 0.0f;
        const float z3 = gsel ? c3 : 0.0f;

        // ---- 9-pass top-scan ----
        float pv = FLT_MAX; int pe = -1;
        float wv8[8]; int ie8[8]; float wsum = 0.f;
        #pragma unroll
        for (int j = 0; j < 9; ++j) {
            float best = -FLT_MAX; int be = 0;
            {   // local ascending strict-> scan over 4 candidates
                int af0 = (z0 < pv) | ((z0 == pv) & (e0     > pe));
                int tk0 = af0 & (z0 > best); best = tk0 ? z0 : best; be = tk0 ? e0     : be;
                int af1 = (z1 < pv) | ((z1 == pv) & (e0 + 1 > pe));
                int tk1 = af1 & (z1 > best); best = tk1 ? z1 : best; be = tk1 ? e0 + 1 : be;
                int af2 = (z2 < pv) | ((z2 == pv) & (e0 + 2 > pe));
                int tk2 = af2 & (z2 > best); best = tk2 ? z2 : best; be = tk2 ? e0 + 2 : be;
                int af3 = (z3 < pv) | ((z3 == pv) & (e0 + 3 > pe));
                int tk3 = af3 & (z3 > best); best = tk3 ? z3 : best; be = tk3 ? e0 + 3 : be;
            }
            #pragma unroll
            for (int m = 1; m < 64; m <<= 1) {    // argmax butterfly: greater, tie -> smaller e
                float ov = __shfl_xor(best, m);
                int   oe = __shfl_xor(be, m);
                int take = (ov > best) | ((ov == best) & (oe < be));
                best = take ? ov : best;
                be   = take ? oe : be;
            }
            if (j > 0) flag = flag || ((pv - best) < TAU);
            if (j < 8) {
                const int ol = be >> 2, oi = be & 3;
                float w0 = __shfl(s0, ol), w1 = __shfl(s1, ol);
                float w2 = __shfl(s2, ol), w3 = __shfl(s3, ol);
                float ow = (oi == 0) ? w0 : (oi == 1) ? w1 : (oi == 2) ? w2 : w3;
                wv8[j] = ow; ie8[j] = be; wsum += ow;
            }
            pv = best; pe = be;
        }

        if (lane == 0) {
            if (flag) {
                int slot = atomicAdd(cnt, 1);
                list[slot] = t;
            }
            float scale = (float)ROUTE_SCALE / wsum;
            #pragma unroll
            for (int j = 0; j < 8; ++j) {
                outw[(size_t)t * 8 + j] = wv8[j] * scale;
                outi[(size_t)t * 8 + j] = (float)ie8[j];
            }
        }
    }
}

// ---------------- Kernel 2a: fp64 dots for flagged tokens — W READ ONCE (LDS) ----------------
// 256 blocks = 64 expert-quads x 4 token-stripes. Block stages its 4x28KB W slice in LDS
// ONCE (112 KB), then streams tokens with NO barriers (4 independent waves = 4 experts),
// 2-token ILP. W L2 traffic: 29 MB total (was n x 7.34 MB). X rows coalesced from global;
// the 64 quad-blocks sweep the same li order -> X rows L2/L3-resident.
__global__ __launch_bounds__(256)
void gate_fix_dot(const float* __restrict__ X, const float* __restrict__ W,
                  const int* __restrict__ cnt, const int* __restrict__ list,
                  double* __restrict__ sig) {
    __shared__ float wlds[4 * DIM];               // 112 KB
    const int tid  = threadIdx.x;
    const int lane = tid & 63;
    const int wv   = tid >> 6;                    // 0..3 -> expert within quad
    const int eb   = blockIdx.x >> 2;             // 0..63
    const int tb   = blockIdx.x & 3;              // token stripe
    const int e    = eb * 4 + wv;
    int n = *cnt; if (n > FIXCAP) n = FIXCAP;

    for (int i = tid; i < DIM; i += 256)          // 7168 float4s, coalesced
        ((float4*)wlds)[i] = ((const float4*)(W + (size_t)eb * 4 * DIM))[i];
    __syncthreads();

    const float* wrow = wlds + wv * DIM;
    for (int li = tb; li < n; li += 8) {          // 2 stripe-tokens per iteration (ILP)
        const int t0  = list[li];
        const int li1 = li + 4;
        const bool v1 = (li1 < n);
        const int t1  = v1 ? list[li1] : t0;
        const float* xr0 = X + (size_t)t0 * DIM;
        const float* xr1 = X + (size_t)t1 * DIM;
        double a0 = 0, a1 = 0, a2 = 0, a3 = 0;
        double b0 = 0, b1 = 0, b2 = 0, b3 = 0;
        for (int kk = 0; kk < DIM / 256; ++kk) {  // 28 iters
            const int k = kk * 256 + lane * 4;
            float4 w4 = *(const float4*)(wrow + k);
            float4 x4 = *(const float4*)(xr0 + k);
            float4 y4 = *(const float4*)(xr1 + k);
            a0 = fma((double)x4.x, (double)w4.x, a0);
            a1 = fma((double)x4.y, (double)w4.y, a1);
            a2 = fma((double)x4.z, (double)w4.z, a2);
            a3 = fma((double)x4.w, (double)w4.w, a3);
            b0 = fma((double)y4.x, (double)w4.x, b0);
            b1 = fma((double)y4.y, (double)w4.y, b1);
            b2 = fma((double)y4.z, (double)w4.z, b2);
            b3 = fma((double)y4.w, (double)w4.w, b3);
        }
        double da = (a0 + a1) + (a2 + a3);
        double db = (b0 + b1) + (b2 + b3);
        #pragma unroll
        for (int m = 1; m < 64; m <<= 1) {
            da += __shfl_xor(da, m);
            db += __shfl_xor(db, m);
        }
        if (lane == 0) {
            sig[(size_t)li * 256 + e] = 1.0 / (1.0 + exp(-da));
            if (v1) sig[(size_t)li1 * 256 + e] = 1.0 / (1.0 + exp(-db));
        }
    }
}

// ---------------- Kernel 2b: fp64 routing for flagged tokens — wave per token ----------------
// Same comparator machinery as gate_route, in double; value semantics identical to the
// R6-verified branchless serial scan (greater, tie -> smaller index == leftmost maximum).
__global__ __launch_bounds__(256)
void gate_fix_route(const float* __restrict__ Bp, float* __restrict__ outw,
                    float* __restrict__ outi, const int* __restrict__ cnt,
                    const int* __restrict__ list, const double* __restrict__ sig) {
    const int lane = threadIdx.x & 63;
    const int wv   = threadIdx.x >> 6;            // 0..3
    const int nw   = gridDim.x * 4;
    const int e0   = lane * 4;
    int n = *cnt; if (n > FIXCAP) n = FIXCAP;

    const float4 bf = ((const float4*)Bp)[lane];
    const double q0 = (double)bf.x, q1 = (double)bf.y, q2 = (double)bf.z, q3 = (double)bf.w;

    for (int li = blockIdx.x * 4 + wv; li < n; li += nw) {
        const int t = list[li];
        const double2 sa = ((const double2*)(sig + (size_t)li * 256))[lane * 2];
        const double2 sb = ((const double2*)(sig + (size_t)li * 256))[lane * 2 + 1];
        const double s0 = sa.x, s1 = sa.y, s2 = sb.x, s3 = sb.y;
        const double c0 = s0 + q0, c1 = s1 + q1, c2 = s2 + q2, c3 = s3 + q3;

        double m1 = -DBL_MAX, m2 = -DBL_MAX;
        m2 = fmax(m2, fmin(m1, c0)); m1 = fmax(m1, c0);
        m2 = fmax(m2, fmin(m1, c1)); m1 = fmax(m1, c1);
        m2 = fmax(m2, fmin(m1, c2)); m1 = fmax(m1, c2);
        m2 = fmax(m2, fmin(m1, c3)); m1 = fmax(m1, c3);
        #pragma unroll
        for (int m = 1; m < 8; m <<= 1) {
            double o1 = __shfl_xor(m1, m);
            double o2 = __shfl_xor(m2, m);
            double hi = fmax(m1, o1);
            double lo = fmax(fmin(m1, o1), fmax(m2, o2));
            m1 = hi; m2 = lo;
        }
        const double gsl = m1 + m2;
        double gs[8];
        #pragma unroll
        for (int j = 0; j < 8; ++j) gs[j] = __shfl(gsl, j * 8);

        unsigned sel = 0;
        #pragma unroll
        for (int r = 0; r < 4; ++r) {
            double best = -DBL_MAX; int bg = 0;
            #pragma unroll
            for (int g = 0; g < 8; ++g) {
                int ok = (((sel >> g) & 1) == 0) & (gs[g] > best);
                best = ok ? gs[g] : best;
                bg   = ok ? g : bg;
            }
            sel |= 1u << bg;
        }
        const int gsel = (sel >> (lane >> 3)) & 1;
        const double z0 = gsel ? c0 : 0.0;
        const double z1 = gsel ? c1 : 0.0;
        const double z2 = gsel ? c2 : 0.0;
        const double z3 = gsel ? c3 : 0.0;

        double pv = DBL_MAX; int pe = -1;
        double wv8[8]; int ie8[8]; double wsum = 0.0;
        #pragma unroll
        for (int j = 0; j < 8; ++j) {
            double best = -DBL_MAX; int be = 0;
            {
                int af0 = (z0 < pv) | ((z0 == pv) & (e0     > pe));
                int tk0 = af0 & (z0 > best); best = tk0 ? z0 : best; be = tk0 ? e0     : be;
                int af1 = (z1 < pv) | ((z1 == pv) & (e0 + 1 > pe));
                int tk1 = af1 & (z1 > best); best = tk1 ? z1 : best; be = tk1 ? e0 + 1 : be;
                int af2 = (z2 < pv) | ((z2 == pv) & (e0 + 2 > pe));
                int tk2 = af2 & (z2 > best); best = tk2 ? z2 : best; be = tk2 ? e0 + 2 : be;
                int af3 = (z3 < pv) | ((z3 == pv) & (e0 + 3 > pe));
                int tk3 = af3 & (z3 > best); best = tk3 ? z3 : best; be = tk3 ? e0 + 3 : be;
            }
            #pragma unroll
            for (int m = 1; m < 64; m <<= 1) {
                double ov = __shfl_xor(best, m);
                int    oe = __shfl_xor(be, m);
                int take = (ov > best) | ((ov == best) & (oe < be));
                best = take ? ov : best;
                be   = take ? oe : be;
            }
            {
                const int ol = be >> 2, oi = be & 3;
                double w0 = __shfl(s0, ol), w1 = __shfl(s1, ol);
                double w2 = __shfl(s2, ol), w3 = __shfl(s3, ol);
                double ow = (oi == 0) ? w0 : (oi == 1) ? w1 : (oi == 2) ? w2 : w3;
                wv8[j] = ow; ie8[j] = be; wsum += ow;
            }
            pv = best; pe = be;
        }
        if (lane == 0) {
            #pragma unroll
            for (int j = 0; j < 8; ++j) {
                outw[(size_t)t * 8 + j] = (float)((wv8[j] / wsum) * ROUTE_SCALE);
                outi[(size_t)t * 8 + j] = (float)ie8[j];
            }
        }
    }
}

extern "C" void kernel_launch(void* const* d_in, const int* in_sizes, int n_in,
                              void* d_out, int out_size, void* d_ws, size_t ws_size,
                              hipStream_t stream) {
    const float* X  = (const float*)d_in[0];
    const float* W  = (const float*)d_in[1];
    const float* Bp = (const float*)d_in[2];
    float* outw = (float*)d_out;
    float* outi = (float*)d_out + (size_t)TOKENS * 8;

    _Float16* Wh = (_Float16*)d_ws;                          // 3.67 MB (chunk-major)
    _Float16* Wl = Wh + WPLANE;                              // 3.67 MB (chunk-major)
    int* cnt  = (int*)(Wl + WPLANE);                         // 16 B slot
    int* list = (int*)((char*)cnt + 16);                     // 64 KB
    float* LG = (float*)(list + TOKENS);                     // 16.8 MB logits
    double* sig = (double*)LG;                               // alias: route consumed LG first

    conv_w        <<<dim3(WPLANE / 1024), dim3(256),  0, stream>>>(W, Wh, Wl, cnt);
    gate_main     <<<dim3(512),           dim3(512),  0, stream>>>(X, Wh, Wl, LG);
    gate_route    <<<dim3(256),           dim3(1024), 0, stream>>>(LG, Bp, outw, outi, cnt, list);
    gate_fix_dot  <<<dim3(256),           dim3(256),  0, stream>>>(X, W, cnt, list, sig);
    gate_fix_route<<<dim3(64),            dim3(256),  0, stream>>>(Bp, outw, outi, cnt, list, sig);
}

// Round 8
// 454.187 us; speedup vs baseline: 2.4292x; 1.0580x over previous
//
#include <hip/hip_runtime.h>
#include <float.h>
#include <math.h>

#define TOKENS 16384
#define DIM    7168
#define NEXP   256
#define BM     32           // tokens per block (R8: halved -> 4 blocks/CU)
#define BK     32
#define NCHUNK (DIM / BK)   // 224
#define ROUTE_SCALE 2.5
#define TAU      6e-6f      // ~50x rms score error of the fp16-split path
#define WSCALE   1024.0f    // lifts W_lo out of fp16 denormal range (exact pow2)
#define WUNSCALE 0.0009765625f
#define FIXCAP   8192       // sig buffer aliases LG (16.8 MB = 8192*256 doubles)

typedef _Float16 half8  __attribute__((ext_vector_type(8)));
typedef _Float16 half4v __attribute__((ext_vector_type(4)));
typedef float    f32x4  __attribute__((ext_vector_type(4)));

#define WPLANE 1835008      // 256*7168 halves per plane

__device__ __forceinline__ _Float16 hi16(float f) { return (_Float16)f; }
__device__ __forceinline__ _Float16 lo16(float f) {
    _Float16 h = (_Float16)f;
    return (_Float16)(f - (float)h);
}

// ---------------- Kernel 0: split (W*1024) into fp16 hi/lo planes, CHUNK-MAJOR ----------------
__global__ __launch_bounds__(256)
void conv_w(const float* __restrict__ W, _Float16* __restrict__ Wh, _Float16* __restrict__ Wl,
            int* __restrict__ cnt) {
    if (blockIdx.x == 0 && threadIdx.x == 0) *cnt = 0;
    int i = blockIdx.x * 256 + threadIdx.x;       // over 458752 float4s (exact)
    int f = i * 4;
    int e = f / DIM;
    int k = f - e * DIM;
    float4 v = ((const float4*)W)[i];
    v.x *= WSCALE; v.y *= WSCALE; v.z *= WSCALE; v.w *= WSCALE;
    half4v h, l;
    h[0] = hi16(v.x); l[0] = lo16(v.x);
    h[1] = hi16(v.y); l[1] = lo16(v.y);
    h[2] = hi16(v.z); l[2] = lo16(v.z);
    h[3] = hi16(v.w); l[3] = lo16(v.w);
    int o = ((k >> 5) << 13) + (e << 5) + (k & 31);   // chunk-major offset
    *(half4v*)(Wh + o) = h;
    *(half4v*)(Wl + o) = l;
}

// ---------------- asm pipeline primitives ----------------
#define MFMA16(a, b, c) __builtin_amdgcn_mfma_f32_16x16x32_f16(a, b, c, 0, 0, 0)

#define VWAIT(n) do { \
    asm volatile("s_waitcnt vmcnt(" #n ")" ::: "memory"); \
    __builtin_amdgcn_sched_barrier(0); \
} while (0)

#define ISSUE_WS(c, S) do { \
    const _Float16* _p = wph0 + (size_t)(c) * 8192; \
    const _Float16* _q = wpl0 + (size_t)(c) * 8192; \
    asm volatile("global_load_dwordx4 %0, %1, off"             : "=&v"(S##h0) : "v"(_p)); \
    asm volatile("global_load_dwordx4 %0, %1, off offset:1024" : "=&v"(S##h1) : "v"(_p)); \
    asm volatile("global_load_dwordx4 %0, %1, off"             : "=&v"(S##l0) : "v"(_q)); \
    asm volatile("global_load_dwordx4 %0, %1, off offset:1024" : "=&v"(S##l1) : "v"(_q)); \
} while (0)

#define ISSUE_XP(gg, XA, XB) do { \
    const float* _px = xsrc + (size_t)(gg) * 64; \
    asm volatile("global_load_dwordx4 %0, %1, off"           : "=&v"(XA) : "v"(_px)); \
    asm volatile("global_load_dwordx4 %0, %1, off offset:16" : "=&v"(XB) : "v"(_px)); \
} while (0)

// lo plane now at +1024 halves (32-row tile)
#define COMPUTE(ABP, BH0, BH1, BL0, BL1) do { \
    const _Float16* _ab = (ABP); \
    half8 ah0 = *(const half8*)(_ab + abase0); \
    half8 ah1 = *(const half8*)(_ab + abase1); \
    half8 al0 = *(const half8*)(_ab + 1024 + abase0); \
    half8 al1 = *(const half8*)(_ab + 1024 + abase1); \
    __builtin_amdgcn_s_setprio(1); \
    acc00 = MFMA16(ah0, BH0, acc00); acc00 = MFMA16(ah0, BL0, acc00); acc00 = MFMA16(al0, BH0, acc00); \
    acc01 = MFMA16(ah0, BH1, acc01); acc01 = MFMA16(ah0, BL1, acc01); acc01 = MFMA16(al0, BH1, acc01); \
    acc10 = MFMA16(ah1, BH0, acc10); acc10 = MFMA16(ah1, BL0, acc10); acc10 = MFMA16(al1, BH0, acc10); \
    acc11 = MFMA16(ah1, BH1, acc11); acc11 = MFMA16(ah1, BL1, acc11); acc11 = MFMA16(al1, BH1, acc11); \
    __builtin_amdgcn_s_setprio(0); \
} while (0)

#define COMPUTE_S(ABP, S) COMPUTE(ABP, S##h0, S##h1, S##l0, S##l1)

#define DUMPF() do { \
    accf00 += acc00; acc00 = (f32x4)(0.0f); \
    accf01 += acc01; acc01 = (f32x4)(0.0f); \
    accf10 += acc10; acc10 = (f32x4)(0.0f); \
    accf11 += acc11; acc11 = (f32x4)(0.0f); \
} while (0)

#define CONVERT_WRITE_XP(dstbuf, XA, XB) do { \
    half8 h8, l8; \
    const float v[8] = {XA.x, XA.y, XA.z, XA.w, XB.x, XB.y, XB.z, XB.w}; \
    _Pragma("unroll") \
    for (int e = 0; e < 8; ++e) { h8[e] = hi16(v[e]); l8[e] = lo16(v[e]); } \
    _Float16* d = hb + (dstbuf) * 4096 + xdst; \
    *(half8*)(d)        = h8; \
    *(half8*)(d + 1024) = l8; \
} while (0)

// ---------------- Kernel 1: fp16-split MFMA GEMM -> logits to global ----------------
// R8: FOUR independent barrier domains per CU. 256 threads (4 waves), tile [32 tokens] x
// [128 experts], grid 1024 = 4 blocks/CU (16 KB LDS, ~70 VGPR each). The only lever that
// has moved this kernel (R4->R5, 716->374) was domain count (1->2) + L2-resident W;
// schedule micro-tuning was 4x neutral. When one block drains at its barrier/VWAIT, the
// other 3 blocks' 12 waves keep issuing. Per-wave work unchanged: 12 MFMA/chunk, same
// 2m x 2n fragments over 32 rows. Same E-split (eh via XCD) -> W-half L2-resident; the
// two eh-blocks of an mt are <=4 bids apart -> X re-read L3-dedups. W-queue arithmetic
// and VWAIT numbers carried over verbatim (identical load counts). Per-(t,e) MFMA product
// order + accf dump cadence (after chunk 16j+15) identical -> logits bit-identical.
__global__ __launch_bounds__(256, 4)
void gate_main(const float* __restrict__ X, const _Float16* __restrict__ Wh,
               const _Float16* __restrict__ Wl, float* __restrict__ LG) {
    __shared__ _Float16 hb[8192];                 // 16 KB: X dbuf [2 buf][2 chunks][2 planes][32][32]

    const int tid  = threadIdx.x;
    const int lane = tid & 63;
    const int ns   = tid >> 6;                    // wave 0..3 = expert slice (32 of 128)
    const int bid  = blockIdx.x;
    const int eh   = (bid >> 2) & 1;              // E-half: XCD 0-3 -> 0, 4-7 -> 1
    const int mt   = (bid >> 3) * 4 + (bid & 3);  // 0..511, each (mt,eh) exactly once
    const int m0   = mt * BM;
    const int fr   = lane & 15;
    const int fk   = lane >> 4;                   // 0..3

    // X staging map: 256 units = 2 chunks x 32 rows x 4 slots (8 floats each)
    const int xcc = tid >> 7;                     // 0..1
    const int xr  = (tid >> 2) & 31;              // 0..31
    const int xs  = tid & 3;                      // 0..3
    const float* xsrc = X + (size_t)(m0 + xr) * DIM + xcc * 32 + xs * 8;
    const int xdst = xcc * 2048 + xr * 32 + ((xs ^ ((xr >> 1) & 3)) << 3);

    // A-fragment LDS bases (halves), swizzled; per-chunk block = [hi 32x32][lo 32x32]
    const int row0 = fr;
    const int row1 = fr + 16;
    const int abase0 = row0 * 32 + ((fk ^ ((row0 >> 1) & 3)) << 3);
    const int abase1 = row1 * 32 + ((fk ^ ((row1 >> 1) & 3)) << 3);

    const int wro = ((eh * 128 + ns * 32 + fr) << 5) + fk * 8;
    const _Float16* wph0 = Wh + wro;
    const _Float16* wpl0 = Wl + wro;

    f32x4 acc00 = {}, acc01 = {}, acc10 = {}, acc11 = {};
    f32x4 accf00 = {}, accf01 = {}, accf10 = {}, accf11 = {};
    half8 S0h0, S0h1, S0l0, S0l1;
    half8 S1h0, S1h1, S1l0, S1l1;
    half8 S2h0, S2h1, S2l0, S2l1;
    half8 S3h0, S3h1, S3l0, S3l1;
    float4 xa, xb;                                // X pair A
    float4 xc, xd;                                // X pair B

    // ---- prologue: stage X(0) plain; drain; issue X(1)->B, W(0)->S0, W(1)->S1 ----
    {
        float4 pa = *(const float4*)(xsrc);
        float4 pb = *(const float4*)(xsrc + 4);
        half8 h8, l8;
        const float v[8] = {pa.x, pa.y, pa.z, pa.w, pb.x, pb.y, pb.z, pb.w};
        #pragma unroll
        for (int e = 0; e < 8; ++e) { h8[e] = hi16(v[e]); l8[e] = lo16(v[e]); }
        *(half8*)(hb + xdst)        = h8;
        *(half8*)(hb + xdst + 1024) = l8;
    }
    asm volatile("s_waitcnt vmcnt(0) lgkmcnt(0)" ::: "memory");
    __builtin_amdgcn_sched_barrier(0);
    ISSUE_XP(1, xc, xd);
    ISSUE_WS(0, S0);
    ISSUE_WS(1, S1);
    __builtin_amdgcn_s_barrier();                 // steady invariant: [Xb(2), S0(4), S1(4)]

    for (int k = 0; k < 55; ++k) {
        const int c4 = k * 4;
        // even group 2k (buf0): chunks 4k,4k+1; VWAIT(4) retires X+W(4k)
        VWAIT(4); ISSUE_XP(2 * k + 2, xa, xb); ISSUE_WS(c4 + 2, S2); COMPUTE_S(hb,        S0);
        VWAIT(6); ISSUE_WS(c4 + 3, S3);                              COMPUTE_S(hb + 2048, S1);
        CONVERT_WRITE_XP(1, xc, xd);
        asm volatile("s_waitcnt lgkmcnt(0)" ::: "memory");
        __builtin_amdgcn_s_barrier();
        // odd group 2k+1 (buf1): chunks 4k+2,4k+3
        VWAIT(4); ISSUE_XP(2 * k + 3, xc, xd); ISSUE_WS(c4 + 4, S0); COMPUTE_S(hb + 4096, S2);
        VWAIT(6); ISSUE_WS(c4 + 5, S1);                              COMPUTE_S(hb + 6144, S3);
        if ((k & 3) == 3) DUMPF();                // after chunk 16j+15: same cadence as verified
        CONVERT_WRITE_XP(0, xa, xb);
        asm volatile("s_waitcnt lgkmcnt(0)" ::: "memory");
        __builtin_amdgcn_s_barrier();
    }
    // group 110 (buf0): chunks 220,221; queue [X(111), W220, W221]
    VWAIT(4); ISSUE_WS(222, S2); COMPUTE_S(hb,        S0);   // retires X(111)+W220
    VWAIT(4); ISSUE_WS(223, S3); COMPUTE_S(hb + 2048, S1);   // retires W221
    CONVERT_WRITE_XP(1, xc, xd);                  // X(111)
    asm volatile("s_waitcnt lgkmcnt(0)" ::: "memory");
    __builtin_amdgcn_s_barrier();
    // group 111 (buf1): chunks 222,223
    VWAIT(4); COMPUTE_S(hb + 4096, S2);
    VWAIT(0); COMPUTE_S(hb + 6144, S3);
    DUMPF();                                      // chunk 223 -> final dump, same cadence

    {
        f32x4 af[2][2] = {{accf00, accf01}, {accf10, accf11}};
        #pragma unroll
        for (int m = 0; m < 2; ++m)
            #pragma unroll
            for (int n = 0; n < 2; ++n)
                #pragma unroll
                for (int r = 0; r < 4; ++r) {
                    int t = m0 + m * 16 + fk * 4 + r;             // D row = (lane>>4)*4 + reg
                    int e = eh * 128 + ns * 32 + n * 16 + fr;     // D col = lane&15
                    LG[(size_t)t * 256 + e] = af[m][n][r] * WUNSCALE;
                }
    }
}

// ---------------- Kernel 1b: routing + margin flags — ONE WAVE PER TOKEN (R7-verified) ----------------
__global__ __launch_bounds__(1024)
void gate_route(const float* __restrict__ LG, const float* __restrict__ Bp,
                float* __restrict__ outw, float* __restrict__ outi,
                int* __restrict__ cnt, int* __restrict__ list) {
    const int lane = threadIdx.x & 63;
    const int wv   = threadIdx.x >> 6;            // 0..15
    const int nw   = gridDim.x * 16;              // total waves
    const int e0   = lane * 4;

    const float4 b4 = ((const float4*)Bp)[lane];  // bias for experts e0..e0+3

    for (int t = blockIdx.x * 16 + wv; t < TOKENS; t += nw) {
        float4 v4 = ((const float4*)LG)[(size_t)t * 64 + lane];
        const float s0 = 1.0f / (1.0f + expf(-v4.x));
        const float s1 = 1.0f / (1.0f + expf(-v4.y));
        const float s2 = 1.0f / (1.0f + expf(-v4.z));
        const float s3 = 1.0f / (1.0f + expf(-v4.w));
        const float c0 = s0 + b4.x, c1 = s1 + b4.y, c2 = s2 + b4.z, c3 = s3 + b4.w;

        // ---- group scores: exact top-2, local then 8-lane merge ----
        float m1 = -FLT_MAX, m2 = -FLT_MAX;
        m2 = fmaxf(m2, fminf(m1, c0)); m1 = fmaxf(m1, c0);
        m2 = fmaxf(m2, fminf(m1, c1)); m1 = fmaxf(m1, c1);
        m2 = fmaxf(m2, fminf(m1, c2)); m1 = fmaxf(m1, c2);
        m2 = fmaxf(m2, fminf(m1, c3)); m1 = fmaxf(m1, c3);
        #pragma unroll
        for (int m = 1; m < 8; m <<= 1) {         // xor 1,2,4 stays within the 8-lane group
            float o1 = __shfl_xor(m1, m);
            float o2 = __shfl_xor(m2, m);
            float hi = fmaxf(m1, o1);
            float lo = fmaxf(fminf(m1, o1), fmaxf(m2, o2));
            m1 = hi; m2 = lo;
        }
        const float gsl = m1 + m2;
        float gs[8];
        #pragma unroll
        for (int j = 0; j < 8; ++j) gs[j] = __shfl(gsl, j * 8);

        // ---- top-4 groups (verbatim serial, redundant per lane) ----
        unsigned sel = 0;
        #pragma unroll
        for (int r = 0; r < 4; ++r) {
            float best = -FLT_MAX; int bg = 0;
            #pragma unroll
            for (int g = 0; g < 8; ++g) {
                int ok = (((sel >> g) & 1) == 0) & (gs[g] > best);
                best = ok ? gs[g] : best;
                bg   = ok ? g : bg;
            }
            sel |= 1u << bg;
        }
        float selmin = FLT_MAX, unselmax = -FLT_MAX;
        #pragma unroll
        for (int g = 0; g < 8; ++g) {
            int s = (sel >> g) & 1;
            selmin   = s ? fminf(selmin, gs[g])   : selmin;
            unselmax = s ? unselmax : fmaxf(unselmax, gs[g]);
        }
        bool flag = (selmin - unselmax) < (2.0f * TAU);

        // ---- masked candidate values (this lane's group is lane>>3) ----
        const int gsel = (sel >> (lane >> 3)) & 1;
        const float z0 = gsel ? c0 : 0.0f;
        const float z1 = gsel ? c1 : 0.0f;
        const float z2 = gsel ? c2 : 0.0f;
        const float z3 = gsel ? c3 : 0.0f;

        // ---- 9-pass top-scan ----
        float pv = FLT_MAX; int pe = -1;
        float wv8[8]; int ie8[8]; float wsum = 0.f;
        #pragma unroll
        for (int j = 0; j < 9; ++j) {
            float best = -FLT_MAX; int be = 0;
            {   // local ascending strict-> scan over 4 candidates
                int af0 = (z0 < pv) | ((z0 == pv) & (e0     > pe));
                int tk0 = af0 & (z0 > best); best = tk0 ? z0 : best; be = tk0 ? e0     : be;
                int af1 = (z1 < pv) | ((z1 == pv) & (e0 + 1 > pe));
                int tk1 = af1 & (z1 > best); best = tk1 ? z1 : best; be = tk1 ? e0 + 1 : be;
                int af2 = (z2 < pv) | ((z2 == pv) & (e0 + 2 > pe));
                int tk2 = af2 & (z2 > best); best = tk2 ? z2 : best; be = tk2 ? e0 + 2 : be;
                int af3 = (z3 < pv) | ((z3 == pv) & (e0 + 3 > pe));
                int tk3 = af3 & (z3 > best); best = tk3 ? z3 : best; be = tk3 ? e0 + 3 : be;
            }
            #pragma unroll
            for (int m = 1; m < 64; m <<= 1) {    // argmax butterfly: greater, tie -> smaller e
                float ov = __shfl_xor(best, m);
                int   oe = __shfl_xor(be, m);
                int take = (ov > best) | ((ov == best) & (oe < be));
                best = take ? ov : best;
                be   = take ? oe : be;
            }
            if (j > 0) flag = flag || ((pv - best) < TAU);
            if (j < 8) {
                const int ol = be >> 2, oi = be & 3;
                float w0 = __shfl(s0, ol), w1 = __shfl(s1, ol);
                float w2 = __shfl(s2, ol), w3 = __shfl(s3, ol);
                float ow = (oi == 0) ? w0 : (oi == 1) ? w1 : (oi == 2) ? w2 : w3;
                wv8[j] = ow; ie8[j] = be; wsum += ow;
            }
            pv = best; pe = be;
        }

        if (lane == 0) {
            if (flag) {
                int slot = atomicAdd(cnt, 1);
                list[slot] = t;
            }
            float scale = (float)ROUTE_SCALE / wsum;
            #pragma unroll
            for (int j = 0; j < 8; ++j) {
                outw[(size_t)t * 8 + j] = wv8[j] * scale;
                outi[(size_t)t * 8 + j] = (float)ie8[j];
            }
        }
    }
}

// ---------------- Kernel 2a: fp64 dots for flagged tokens — W READ ONCE (R7-verified) ----------------
__global__ __launch_bounds__(256)
void gate_fix_dot(const float* __restrict__ X, const float* __restrict__ W,
                  const int* __restrict__ cnt, const int* __restrict__ list,
                  double* __restrict__ sig) {
    __shared__ float wlds[4 * DIM];               // 112 KB
    const int tid  = threadIdx.x;
    const int lane = tid & 63;
    const int wv   = tid >> 6;                    // 0..3 -> expert within quad
    const int eb   = blockIdx.x >> 2;             // 0..63
    const int tb   = blockIdx.x & 3;              // token stripe
    const int e    = eb * 4 + wv;
    int n = *cnt; if (n > FIXCAP) n = FIXCAP;

    for (int i = tid; i < DIM; i += 256)          // 7168 float4s, coalesced
        ((float4*)wlds)[i] = ((const float4*)(W + (size_t)eb * 4 * DIM))[i];
    __syncthreads();

    const float* wrow = wlds + wv * DIM;
    for (int li = tb; li < n; li += 8) {          // 2 stripe-tokens per iteration (ILP)
        const int t0  = list[li];
        const int li1 = li + 4;
        const bool v1 = (li1 < n);
        const int t1  = v1 ? list[li1] : t0;
        const float* xr0 = X + (size_t)t0 * DIM;
        const float* xr1 = X + (size_t)t1 * DIM;
        double a0 = 0, a1 = 0, a2 = 0, a3 = 0;
        double b0 = 0, b1 = 0, b2 = 0, b3 = 0;
        for (int kk = 0; kk < DIM / 256; ++kk) {  // 28 iters
            const int k = kk * 256 + lane * 4;
            float4 w4 = *(const float4*)(wrow + k);
            float4 x4 = *(const float4*)(xr0 + k);
            float4 y4 = *(const float4*)(xr1 + k);
            a0 = fma((double)x4.x, (double)w4.x, a0);
            a1 = fma((double)x4.y, (double)w4.y, a1);
            a2 = fma((double)x4.z, (double)w4.z, a2);
            a3 = fma((double)x4.w, (double)w4.w, a3);
            b0 = fma((double)y4.x, (double)w4.x, b0);
            b1 = fma((double)y4.y, (double)w4.y, b1);
            b2 = fma((double)y4.z, (double)w4.z, b2);
            b3 = fma((double)y4.w, (double)w4.w, b3);
        }
        double da = (a0 + a1) + (a2 + a3);
        double db = (b0 + b1) + (b2 + b3);
        #pragma unroll
        for (int m = 1; m < 64; m <<= 1) {
            da += __shfl_xor(da, m);
            db += __shfl_xor(db, m);
        }
        if (lane == 0) {
            sig[(size_t)li * 256 + e] = 1.0 / (1.0 + exp(-da));
            if (v1) sig[(size_t)li1 * 256 + e] = 1.0 / (1.0 + exp(-db));
        }
    }
}

// ---------------- Kernel 2b: fp64 routing for flagged tokens — wave per token (R7-verified) ----------------
__global__ __launch_bounds__(256)
void gate_fix_route(const float* __restrict__ Bp, float* __restrict__ outw,
                    float* __restrict__ outi, const int* __restrict__ cnt,
                    const int* __restrict__ list, const double* __restrict__ sig) {
    const int lane = threadIdx.x & 63;
    const int wv   = threadIdx.x >> 6;            // 0..3
    const int nw   = gridDim.x * 4;
    const int e0   = lane * 4;
    int n = *cnt; if (n > FIXCAP) n = FIXCAP;

    const float4 bf = ((const float4*)Bp)[lane];
    const double q0 = (double)bf.x, q1 = (double)bf.y, q2 = (double)bf.z, q3 = (double)bf.w;

    for (int li = blockIdx.x * 4 + wv; li < n; li += nw) {
        const int t = list[li];
        const double2 sa = ((const double2*)(sig + (size_t)li * 256))[lane * 2];
        const double2 sb = ((const double2*)(sig + (size_t)li * 256))[lane * 2 + 1];
        const double s0 = sa.x, s1 = sa.y, s2 = sb.x, s3 = sb.y;
        const double c0 = s0 + q0, c1 = s1 + q1, c2 = s2 + q2, c3 = s3 + q3;

        double m1 = -DBL_MAX, m2 = -DBL_MAX;
        m2 = fmax(m2, fmin(m1, c0)); m1 = fmax(m1, c0);
        m2 = fmax(m2, fmin(m1, c1)); m1 = fmax(m1, c1);
        m2 = fmax(m2, fmin(m1, c2)); m1 = fmax(m1, c2);
        m2 = fmax(m2, fmin(m1, c3)); m1 = fmax(m1, c3);
        #pragma unroll
        for (int m = 1; m < 8; m <<= 1) {
            double o1 = __shfl_xor(m1, m);
            double o2 = __shfl_xor(m2, m);
            double hi = fmax(m1, o1);
            double lo = fmax(fmin(m1, o1), fmax(m2, o2));
            m1 = hi; m2 = lo;
        }
        const double gsl = m1 + m2;
        double gs[8];
        #pragma unroll
        for (int j = 0; j < 8; ++j) gs[j] = __shfl(gsl, j * 8);

        unsigned sel = 0;
        #pragma unroll
        for (int r = 0; r < 4; ++r) {
            double best = -DBL_MAX; int bg = 0;
            #pragma unroll
            for (int g = 0; g < 8; ++g) {
                int ok = (((sel >> g) & 1) == 0) & (gs[g] > best);
                best = ok ? gs[g] : best;
                bg   = ok ? g : bg;
            }
            sel |= 1u << bg;
        }
        const int gsel = (sel >> (lane >> 3)) & 1;
        const double z0 = gsel ? c0 : 0.0;
        const double z1 = gsel ? c1 : 0.0;
        const double z2 = gsel ? c2 : 0.0;
        const double z3 = gsel ? c3 : 0.0;

        double pv = DBL_MAX; int pe = -1;
        double wv8[8]; int ie8[8]; double wsum = 0.0;
        #pragma unroll
        for (int j = 0; j < 8; ++j) {
            double best = -DBL_MAX; int be = 0;
            {
                int af0 = (z0 < pv) | ((z0 == pv) & (e0     > pe));
                int tk0 = af0 & (z0 > best); best = tk0 ? z0 : best; be = tk0 ? e0     : be;
                int af1 = (z1 < pv) | ((z1 == pv) & (e0 + 1 > pe));
                int tk1 = af1 & (z1 > best); best = tk1 ? z1 : best; be = tk1 ? e0 + 1 : be;
                int af2 = (z2 < pv) | ((z2 == pv) & (e0 + 2 > pe));
                int tk2 = af2 & (z2 > best); best = tk2 ? z2 : best; be = tk2 ? e0 + 2 : be;
                int af3 = (z3 < pv) | ((z3 == pv) & (e0 + 3 > pe));
                int tk3 = af3 & (z3 > best); best = tk3 ? z3 : best; be = tk3 ? e0 + 3 : be;
            }
            #pragma unroll
            for (int m = 1; m < 64; m <<= 1) {
                double ov = __shfl_xor(best, m);
                int    oe = __shfl_xor(be, m);
                int take = (ov > best) | ((ov == best) & (oe < be));
                best = take ? ov : best;
                be   = take ? oe : be;
            }
            {
                const int ol = be >> 2, oi = be & 3;
                double w0 = __shfl(s0, ol), w1 = __shfl(s1, ol);
                double w2 = __shfl(s2, ol), w3 = __shfl(s3, ol);
                double ow = (oi == 0) ? w0 : (oi == 1) ? w1 : (oi == 2) ? w2 : w3;
                wv8[j] = ow; ie8[j] = be; wsum += ow;
            }
            pv = best; pe = be;
        }
        if (lane == 0) {
            #pragma unroll
            for (int j = 0; j < 8; ++j) {
                outw[(size_t)t * 8 + j] = (float)((wv8[j] / wsum) * ROUTE_SCALE);
                outi[(size_t)t * 8 + j] = (float)ie8[j];
            }
        }
    }
}

extern "C" void kernel_launch(void* const* d_in, const int* in_sizes, int n_in,
                              void* d_out, int out_size, void* d_ws, size_t ws_size,
                              hipStream_t stream) {
    const float* X  = (const float*)d_in[0];
    const float* W  = (const float*)d_in[1];
    const float* Bp = (const float*)d_in[2];
    float* outw = (float*)d_out;
    float* outi = (float*)d_out + (size_t)TOKENS * 8;

    _Float16* Wh = (_Float16*)d_ws;                          // 3.67 MB (chunk-major)
    _Float16* Wl = Wh + WPLANE;                              // 3.67 MB (chunk-major)
    int* cnt  = (int*)(Wl + WPLANE);                         // 16 B slot
    int* list = (int*)((char*)cnt + 16);                     // 64 KB
    float* LG = (float*)(list + TOKENS);                     // 16.8 MB logits
    double* sig = (double*)LG;                               // alias: route consumed LG first

    conv_w        <<<dim3(WPLANE / 1024), dim3(256),  0, stream>>>(W, Wh, Wl, cnt);
    gate_main     <<<dim3(1024),          dim3(256),  0, stream>>>(X, Wh, Wl, LG);
    gate_route    <<<dim3(256),           dim3(1024), 0, stream>>>(LG, Bp, outw, outi, cnt, list);
    gate_fix_dot  <<<dim3(256),           dim3(256),  0, stream>>>(X, W, cnt, list, sig);
    gate_fix_route<<<dim3(64),            dim3(256),  0, stream>>>(Bp, outw, outi, cnt, list, sig);
}